// Round 6
// baseline (902.385 us; speedup 1.0000x reference)
//
#include <hip/hip_runtime.h>
#include <type_traits>

#define FDIM 320
#define NHEADS 10
#define NGR 256

typedef __bf16 bf16x8 __attribute__((ext_vector_type(8)));
typedef float f32x4 __attribute__((ext_vector_type(4)));

// ---------------- weight transpose+convert: Wt[c*320+k] = (bf16)W[k*320+c] --
__global__ void wconv_kernel(const float* __restrict__ W, __bf16* __restrict__ Wt) {
  int idx = blockIdx.x * 256 + threadIdx.x;
  int k = idx / FDIM, c = idx - k * FDIM;
  Wt[c * FDIM + k] = (__bf16)W[idx];
}

// ---------------- node GEMM v2: full-K in LDS, one barrier ----------------
// C[M,320] = A[M,320] * W[320,320].  Block: 64 rows x 160-col half of W.
// Stage A(64x320 bf16, padded) + B-half(160x320 bf16, padded) once; 1 barrier;
// then 100 MFMA/wave from LDS, no inner barriers, no re-staging.
#define APAD 328   // row stride in elems (656B): bank stride 4 -> 2-way max (free)

template<typename TA>
__global__ __launch_bounds__(256, 1) void gemm320f_kernel(
    const TA* __restrict__ A, const __bf16* __restrict__ Wt,
    __bf16* __restrict__ C, int M)
{
  __shared__ __bf16 As[64 * APAD];     // 41,984 B
  __shared__ __bf16 Bs[160 * APAD];    // 104,960 B  (total 146,944 B)

  const int tid = threadIdx.x;
  const int lane = tid & 63;
  const int w = tid >> 6;          // 4 waves
  const int wr = w & 1;            // row group: 32 rows
  const int wcg = w >> 1;          // col group: 80 cols
  const int r = lane & 15, kg = lane >> 4;
  const int m0 = blockIdx.x * 64;
  const int n0 = blockIdx.y * 160; // N-half

  // ---- stage B half: 160 cols x 320 k, 6400 8-elem chunks, 25/thread ----
  #pragma unroll
  for (int i = 0; i < 25; i++) {
    int ch = tid + i * 256;
    int col = ch / 40;
    int ko = (ch - col * 40) * 8;
    bf16x8 v = *(const bf16x8*)(Wt + (size_t)(n0 + col) * FDIM + ko);
    *(bf16x8*)&Bs[col * APAD + ko] = v;
  }
  // ---- stage A: 64 rows x 320 k; thread = (row, quarter of 80 elems) ----
  {
    int row = tid >> 2, q = tid & 3;
    int gm = m0 + row;
    if constexpr (std::is_same_v<TA, float>) {
      #pragma unroll
      for (int i = 0; i < 10; i++) {
        bf16x8 v = {};
        if (gm < M) {
          const float4* ap = (const float4*)(A + (size_t)gm * FDIM + q * 80 + i * 8);
          float4 u0 = ap[0], u1 = ap[1];
          v[0]=(__bf16)u0.x; v[1]=(__bf16)u0.y; v[2]=(__bf16)u0.z; v[3]=(__bf16)u0.w;
          v[4]=(__bf16)u1.x; v[5]=(__bf16)u1.y; v[6]=(__bf16)u1.z; v[7]=(__bf16)u1.w;
        }
        *(bf16x8*)&As[row * APAD + q * 80 + i * 8] = v;
      }
    } else {
      #pragma unroll
      for (int i = 0; i < 10; i++) {
        bf16x8 v = {};
        if (gm < M) v = *(const bf16x8*)(A + (size_t)gm * FDIM + q * 80 + i * 8);
        *(bf16x8*)&As[row * APAD + q * 80 + i * 8] = v;
      }
    }
  }
  __syncthreads();

  // ---- compute: wave = 32 rows x 80 cols; per k: 2 A-reads + 5 B-reads, 10 MFMA
  f32x4 acc0[5], acc1[5];
  #pragma unroll
  for (int i = 0; i < 5; i++) { acc0[i] = (f32x4){0,0,0,0}; acc1[i] = (f32x4){0,0,0,0}; }

  #pragma unroll
  for (int k = 0; k < 10; k++) {
    bf16x8 a0 = *(const bf16x8*)&As[(wr*32 + r)      * APAD + k*32 + kg*8];
    bf16x8 a1 = *(const bf16x8*)&As[(wr*32 + 16 + r) * APAD + k*32 + kg*8];
    #pragma unroll
    for (int nf = 0; nf < 5; nf++) {
      bf16x8 b = *(const bf16x8*)&Bs[(wcg*80 + nf*16 + r) * APAD + k*32 + kg*8];
      acc0[nf] = __builtin_amdgcn_mfma_f32_16x16x32_bf16(a0, b, acc0[nf], 0, 0, 0);
      acc1[nf] = __builtin_amdgcn_mfma_f32_16x16x32_bf16(a1, b, acc1[nf], 0, 0, 0);
    }
  }

  // ---- store ----
  #pragma unroll
  for (int nf = 0; nf < 5; nf++) {
    int gn = n0 + wcg*80 + nf*16 + r;
    #pragma unroll
    for (int q = 0; q < 4; q++) {
      int gm0 = m0 + wr*32 + kg*4 + q;
      if (gm0 < M)       C[(size_t)gm0 * FDIM + gn] = (__bf16)acc0[nf][q];
      int gm1 = gm0 + 16;
      if (gm1 < M)       C[(size_t)gm1 * FDIM + gn] = (__bf16)acc1[nf][q];
    }
  }
}

// ---------------- generic GEMM (FC layers): C = A*B, f32 in/out ------------
#define BM 128
#define BN 64
#define BK 32
#define LSTR 56

template<int FLAGS>  // bit0: relu, bit1: bias
__global__ __launch_bounds__(256) void gemm_bf16_kernel(
    const float* __restrict__ A, const float* __restrict__ B,
    float* __restrict__ C, const float* __restrict__ bias,
    int M, int N, int K, int ldc)
{
  __shared__ __bf16 As[BM * LSTR];
  __shared__ __bf16 Bs[BN * LSTR];

  const int tid = threadIdx.x;
  const int lane = tid & 63;
  const int w = tid >> 6;
  const int wm = w >> 1, wn = w & 1;
  const int r = lane & 15, kg = lane >> 4;
  const int m0 = blockIdx.x * BM, n0 = blockIdx.y * BN;

  f32x4 acc[4][2];
  #pragma unroll
  for (int i = 0; i < 4; i++)
    #pragma unroll
    for (int j = 0; j < 2; j++)
      acc[i][j] = (f32x4){0.f, 0.f, 0.f, 0.f};

  const int arow = tid >> 1, ahalf = tid & 1;
  const int bk = tid >> 3, bn = (tid & 7) * 8;

  for (int k0 = 0; k0 < K; k0 += BK) {
    __syncthreads();
    {
      int gm = m0 + arow;
      int kbase = k0 + ahalf * 16;
      float tmp[16];
      if (gm < M && kbase + 16 <= K) {
        const float4* ap = (const float4*)(A + (size_t)gm * K + kbase);
        #pragma unroll
        for (int q = 0; q < 4; q++) {
          float4 v = ap[q];
          tmp[q*4+0] = v.x; tmp[q*4+1] = v.y; tmp[q*4+2] = v.z; tmp[q*4+3] = v.w;
        }
      } else {
        #pragma unroll
        for (int q = 0; q < 16; q++) {
          int kk = kbase + q;
          tmp[q] = (gm < M && kk < K) ? A[(size_t)gm * K + kk] : 0.f;
        }
      }
      bf16x8 v0, v1;
      #pragma unroll
      for (int q = 0; q < 8; q++) { v0[q] = (__bf16)tmp[q]; v1[q] = (__bf16)tmp[q+8]; }
      bf16x8* dp = (bf16x8*)&As[arow * LSTR + ahalf * 16];
      dp[0] = v0; dp[1] = v1;
    }
    {
      int gk = k0 + bk;
      float tb[8];
      if (gk < K && n0 + bn + 8 <= N) {
        const float4* bp = (const float4*)(B + (size_t)gk * N + n0 + bn);
        float4 u0 = bp[0], u1 = bp[1];
        tb[0]=u0.x; tb[1]=u0.y; tb[2]=u0.z; tb[3]=u0.w;
        tb[4]=u1.x; tb[5]=u1.y; tb[6]=u1.z; tb[7]=u1.w;
      } else {
        #pragma unroll
        for (int q = 0; q < 8; q++) {
          int gn = n0 + bn + q;
          tb[q] = (gk < K && gn < N) ? B[(size_t)gk * N + gn] : 0.f;
        }
      }
      #pragma unroll
      for (int q = 0; q < 8; q++) Bs[(bn + q) * LSTR + bk] = (__bf16)tb[q];
    }
    __syncthreads();
    bf16x8 af[4], bfr[2];
    #pragma unroll
    for (int mf = 0; mf < 4; mf++)
      af[mf] = *(const bf16x8*)&As[(wm*64 + mf*16 + r) * LSTR + kg*8];
    #pragma unroll
    for (int nf = 0; nf < 2; nf++)
      bfr[nf] = *(const bf16x8*)&Bs[(wn*32 + nf*16 + r) * LSTR + kg*8];
    #pragma unroll
    for (int mf = 0; mf < 4; mf++)
      #pragma unroll
      for (int nf = 0; nf < 2; nf++)
        acc[mf][nf] = __builtin_amdgcn_mfma_f32_16x16x32_bf16(af[mf], bfr[nf], acc[mf][nf], 0, 0, 0);
  }

  #pragma unroll
  for (int mf = 0; mf < 4; mf++) {
    #pragma unroll
    for (int nf = 0; nf < 2; nf++) {
      #pragma unroll
      for (int q = 0; q < 4; q++) {
        int gm = m0 + wm*64 + mf*16 + kg*4 + q;
        int gn = n0 + wn*32 + nf*16 + r;
        if (gm < M && gn < N) {
          float v = acc[mf][nf][q];
          if (FLAGS & 2) v += bias[gn];
          if (FLAGS & 1) v = fmaxf(v, 0.f);
          C[(size_t)gm * ldc + gn] = v;
        }
      }
    }
  }
}

// ---------------- split-K GEMM: P[s][M][N] partials ----------------
__global__ __launch_bounds__(256) void gemm_splitk_kernel(
    const float* __restrict__ A, const float* __restrict__ B,
    float* __restrict__ P, int M, int N, int K, int KS)
{
  __shared__ __bf16 As[BM * LSTR];
  __shared__ __bf16 Bs[BN * LSTR];

  const int tid = threadIdx.x;
  const int lane = tid & 63;
  const int w = tid >> 6;
  const int wm = w >> 1, wn = w & 1;
  const int r = lane & 15, kg = lane >> 4;
  const int m0 = blockIdx.x * BM, n0 = blockIdx.y * BN;
  const int kstart = blockIdx.z * KS;
  const int kend = min(K, kstart + KS);

  f32x4 acc[4][2];
  #pragma unroll
  for (int i = 0; i < 4; i++)
    #pragma unroll
    for (int j = 0; j < 2; j++)
      acc[i][j] = (f32x4){0.f, 0.f, 0.f, 0.f};

  const int arow = tid >> 1, ahalf = tid & 1;
  const int bk = tid >> 3, bn = (tid & 7) * 8;

  for (int k0 = kstart; k0 < kend; k0 += BK) {
    __syncthreads();
    {
      int gm = m0 + arow;
      int kbase = k0 + ahalf * 16;
      float tmp[16];
      if (gm < M && kbase + 16 <= kend) {
        const float4* ap = (const float4*)(A + (size_t)gm * K + kbase);
        #pragma unroll
        for (int q = 0; q < 4; q++) {
          float4 v = ap[q];
          tmp[q*4+0] = v.x; tmp[q*4+1] = v.y; tmp[q*4+2] = v.z; tmp[q*4+3] = v.w;
        }
      } else {
        #pragma unroll
        for (int q = 0; q < 16; q++) {
          int kk = kbase + q;
          tmp[q] = (gm < M && kk < kend) ? A[(size_t)gm * K + kk] : 0.f;
        }
      }
      bf16x8 v0, v1;
      #pragma unroll
      for (int q = 0; q < 8; q++) { v0[q] = (__bf16)tmp[q]; v1[q] = (__bf16)tmp[q+8]; }
      bf16x8* dp = (bf16x8*)&As[arow * LSTR + ahalf * 16];
      dp[0] = v0; dp[1] = v1;
    }
    {
      int gk = k0 + bk;
      float tb[8];
      if (gk < kend && n0 + bn + 8 <= N) {
        const float4* bp = (const float4*)(B + (size_t)gk * N + n0 + bn);
        float4 u0 = bp[0], u1 = bp[1];
        tb[0]=u0.x; tb[1]=u0.y; tb[2]=u0.z; tb[3]=u0.w;
        tb[4]=u1.x; tb[5]=u1.y; tb[6]=u1.z; tb[7]=u1.w;
      } else {
        #pragma unroll
        for (int q = 0; q < 8; q++) {
          int gn = n0 + bn + q;
          tb[q] = (gk < kend && gn < N) ? B[(size_t)gk * N + gn] : 0.f;
        }
      }
      #pragma unroll
      for (int q = 0; q < 8; q++) Bs[(bn + q) * LSTR + bk] = (__bf16)tb[q];
    }
    __syncthreads();
    bf16x8 af[4], bfr[2];
    #pragma unroll
    for (int mf = 0; mf < 4; mf++)
      af[mf] = *(const bf16x8*)&As[(wm*64 + mf*16 + r) * LSTR + kg*8];
    #pragma unroll
    for (int nf = 0; nf < 2; nf++)
      bfr[nf] = *(const bf16x8*)&Bs[(wn*32 + nf*16 + r) * LSTR + kg*8];
    #pragma unroll
    for (int mf = 0; mf < 4; mf++)
      #pragma unroll
      for (int nf = 0; nf < 2; nf++)
        acc[mf][nf] = __builtin_amdgcn_mfma_f32_16x16x32_bf16(af[mf], bfr[nf], acc[mf][nf], 0, 0, 0);
  }

  float* Pp = P + (size_t)blockIdx.z * M * N;
  #pragma unroll
  for (int mf = 0; mf < 4; mf++) {
    #pragma unroll
    for (int nf = 0; nf < 2; nf++) {
      #pragma unroll
      for (int q = 0; q < 4; q++) {
        int gm = m0 + wm*64 + mf*16 + kg*4 + q;
        int gn = n0 + wn*32 + nf*16 + r;
        if (gm < M && gn < N)
          Pp[(size_t)gm * N + gn] = acc[mf][nf][q];
      }
    }
  }
}

// reduce partials; STACK: rows M/2.. go to cols N.. (fc_g2 branch packing)
template<int FLAGS, bool STACK>
__global__ void reduce_kernel(const float* __restrict__ P, float* __restrict__ C,
                              const float* __restrict__ bias, int M, int N, int S, int ldc)
{
  int i = blockIdx.x * 256 + threadIdx.x;
  if (i >= M * N) return;
  float v = 0.f;
  for (int s = 0; s < S; s++) v += P[(size_t)s * M * N + i];
  int row = i / N, col = i - row * N;
  if (FLAGS & 2) v += bias[col];
  if (FLAGS & 1) v = fmaxf(v, 0.f);
  if (STACK) { if (row >= (M >> 1)) { row -= (M >> 1); col += N; } }
  C[(size_t)row * ldc + col] = v;
}

// ---------------- CSR build ----------------
__global__ void count_kernel(const int* __restrict__ dst, int* __restrict__ cnt, int E) {
  int e = blockIdx.x * 256 + threadIdx.x;
  if (e < E) atomicAdd(&cnt[dst[e]], 1);
}

__global__ void bsum_kernel(const int* __restrict__ cnt, int* __restrict__ bsum, int n) {
  __shared__ int wp[4];
  int tid = threadIdx.x, lane = tid & 63, wid = tid >> 6;
  int i = blockIdx.x * 256 + tid;
  int v = (i < n) ? cnt[i] : 0;
  #pragma unroll
  for (int off = 32; off >= 1; off >>= 1) v += __shfl_xor(v, off, 64);
  if (lane == 0) wp[wid] = v;
  __syncthreads();
  if (tid == 0) bsum[blockIdx.x] = wp[0] + wp[1] + wp[2] + wp[3];
}

__global__ void bscan_kernel(int* __restrict__ bsum, int nb) {
  __shared__ int wp[4];
  int tid = threadIdx.x, lane = tid & 63, wid = tid >> 6;
  int v = (tid < nb) ? bsum[tid] : 0;
  int xv = v;
  #pragma unroll
  for (int off = 1; off < 64; off <<= 1) {
    int y = __shfl_up(xv, off, 64);
    if (lane >= off) xv += y;
  }
  if (lane == 63) wp[wid] = xv;
  __syncthreads();
  if (tid == 0) { int s = 0; for (int k = 0; k < 4; k++) { int t = wp[k]; wp[k] = s; s += t; } }
  __syncthreads();
  if (tid < nb) bsum[tid] = wp[wid] + xv - v;   // exclusive
}

__global__ void rpfill_kernel(const int* __restrict__ cnt, const int* __restrict__ bsum,
                              int* __restrict__ rp, float* __restrict__ dinv, int n, int E) {
  __shared__ int wp[4];
  int tid = threadIdx.x, lane = tid & 63, wid = tid >> 6;
  int i = blockIdx.x * 256 + tid;
  int v = (i < n) ? cnt[i] : 0;
  int xv = v;
  #pragma unroll
  for (int off = 1; off < 64; off <<= 1) {
    int y = __shfl_up(xv, off, 64);
    if (lane >= off) xv += y;
  }
  if (lane == 63) wp[wid] = xv;
  __syncthreads();
  if (tid == 0) { int s = 0; for (int k = 0; k < 4; k++) { int t = wp[k]; wp[k] = s; s += t; } }
  __syncthreads();
  if (i < n) {
    rp[i] = bsum[blockIdx.x] + wp[wid] + xv - v;
    dinv[i] = rsqrtf((float)(v + 1));
  }
  if (blockIdx.x == 0 && tid == 0) rp[n] = E;
}

__global__ void fill_kernel(const int* __restrict__ src, const int* __restrict__ dst,
                            const int* __restrict__ rp, int* __restrict__ fil,
                            int* __restrict__ csr, int* __restrict__ csr_dst, int E) {
  int e = blockIdx.x * 256 + threadIdx.x;
  if (e < E) {
    int d = dst[e];
    int pos = rp[d] + atomicAdd(&fil[d], 1);
    csr[pos] = src[e];
    csr_dst[pos] = d;
  }
}

// ---------------- GCN aggregate (wave/node, chunked edge preload, bf16 h) --
__global__ void gcn_agg_kernel(const __bf16* __restrict__ h, const int* __restrict__ rp,
                               const int* __restrict__ csr, const float* __restrict__ dinv,
                               const float* __restrict__ bias, __bf16* __restrict__ out, int n)
{
  const int lane = threadIdx.x & 63;
  const int v = blockIdx.x * 4 + (threadIdx.x >> 6);
  if (v >= n) return;
  const float dv = dinv[v];
  const int e0 = rp[v], e1 = rp[v + 1];
  float acc[5];
  #pragma unroll
  for (int j = 0; j < 5; j++) acc[j] = dv * (float)h[(size_t)v * FDIM + lane + 64 * j];
  for (int base = e0; base < e1; base += 64) {
    int nn = min(64, e1 - base);
    int s_l = (lane < nn) ? csr[base + lane] : 0;
    float d_l = (lane < nn) ? dinv[s_l] : 0.f;
    for (int j2 = 0; j2 < nn; j2++) {
      int sj = __shfl(s_l, j2, 64);
      float cj = __shfl(d_l, j2, 64);
      const __bf16* hs = h + (size_t)sj * FDIM;
      #pragma unroll
      for (int j = 0; j < 5; j++) acc[j] += cj * (float)hs[lane + 64 * j];
    }
  }
  #pragma unroll
  for (int j = 0; j < 5; j++) {
    float rr = dv * acc[j] + bias[lane + 64 * j];
    out[(size_t)v * FDIM + lane + 64 * j] = (__bf16)fmaxf(rr, 0.f);
  }
}

// ---------------- GAT attention scores a_s, a_d (one wave per node) --------
__global__ void gat_scores_kernel(const __bf16* __restrict__ h, const float* __restrict__ att_s,
                                  const float* __restrict__ att_d, float* __restrict__ as_,
                                  float* __restrict__ ad_, int n)
{
  const int lane = threadIdx.x & 63;
  const int v = blockIdx.x * 4 + (threadIdx.x >> 6);
  if (v >= n) return;
  const int c = lane & 31;
  const int hh = lane >> 5;
  #pragma unroll
  for (int j = 0; j < 5; j++) {
    int head = hh * 5 + j;
    float xv = (float)h[(size_t)v * FDIM + head * 32 + c];
    float ps = xv * att_s[head * 32 + c];
    float pd = xv * att_d[head * 32 + c];
    #pragma unroll
    for (int off = 1; off < 32; off <<= 1) {
      ps += __shfl_xor(ps, off, 64);
      pd += __shfl_xor(pd, off, 64);
    }
    if (c == 0) { as_[v * NHEADS + head] = ps; ad_[v * NHEADS + head] = pd; }
  }
}

__device__ __forceinline__ float lrelu(float x) { return x > 0.f ? x : 0.2f * x; }

// ---------------- edge-parallel raw scores, PLANE layout es[t*E + e] -------
__global__ void escore_kernel(const int* __restrict__ csr, const int* __restrict__ csr_dst,
                              const float* __restrict__ as_, const float* __restrict__ ad_,
                              float* __restrict__ es, int E)
{
  int i = blockIdx.x * 256 + threadIdx.x;
  if (i >= E) return;
  int s = csr[i], d = csr_dst[i];
  const float* ap = as_ + (size_t)s * NHEADS;
  const float* dp = ad_ + (size_t)d * NHEADS;
  #pragma unroll
  for (int t = 0; t < NHEADS; t++) es[(size_t)t * E + i] = lrelu(ap[t] + dp[t]);
}

// ---------------- per-(node,head) segment max + denom; head = blockIdx.y ---
__global__ void mdenom_kernel(const float* __restrict__ es, const int* __restrict__ rp,
                              const float* __restrict__ as_, const float* __restrict__ ad_,
                              float* __restrict__ mseg, float* __restrict__ invden,
                              float* __restrict__ aself, int n, int E)
{
  int v = blockIdx.x * 256 + threadIdx.x;
  if (v >= n) return;
  int t = blockIdx.y;
  int e0 = rp[v], e1 = rp[v + 1];
  float esf = lrelu(as_[v * NHEADS + t] + ad_[v * NHEADS + t]);
  const float* ep = es + (size_t)t * E;
  float m = esf;
  for (int e = e0; e < e1; e++) m = fmaxf(m, ep[e]);
  float den = __expf(esf - m);
  float pself = den;
  for (int e = e0; e < e1; e++) den += __expf(ep[e] - m);
  float inv = 1.f / den;
  mseg[v * NHEADS + t] = m;
  invden[v * NHEADS + t] = inv;
  aself[v * NHEADS + t] = pself * inv;
}

// ---------------- edge-parallel alpha: planes -> interleaved [e][10] -------
__global__ void alpha_kernel(const int* __restrict__ csr_dst, const float* __restrict__ mseg,
                             const float* __restrict__ invden, const float* __restrict__ es,
                             float* __restrict__ aint, int E)
{
  int i = blockIdx.x * 256 + threadIdx.x;
  if (i >= E) return;
  int d = csr_dst[i];
  const float* mp = mseg + (size_t)d * NHEADS;
  const float* ip = invden + (size_t)d * NHEADS;
  float* op = aint + (size_t)i * NHEADS;
  #pragma unroll
  for (int t = 0; t < NHEADS; t++)
    op[t] = __expf(es[(size_t)t * E + i] - mp[t]) * ip[t];
}

// ---------------- GAT aggregate (wave/node, interleaved alpha, bf16 h) -----
__global__ void gat_agg_kernel(const __bf16* __restrict__ h, const int* __restrict__ rp,
                               const int* __restrict__ csr, const float* __restrict__ aint,
                               const float* __restrict__ aself, const float* __restrict__ bias,
                               __bf16* __restrict__ out, int n)
{
  const int lane = threadIdx.x & 63;
  const int v = blockIdx.x * 4 + (threadIdx.x >> 6);
  if (v >= n) return;
  const int hb = lane >> 5;   // head of channel lane+64j is 2j+hb
  const int e0 = rp[v], e1 = rp[v + 1];
  const float* asf = aself + (size_t)v * NHEADS;
  float acc[5];
  #pragma unroll
  for (int j = 0; j < 5; j++)
    acc[j] = asf[2 * j + hb] * (float)h[(size_t)v * FDIM + lane + 64 * j];
  for (int base = e0; base < e1; base += 64) {
    int nn = min(64, e1 - base);
    int s_l = (lane < nn) ? csr[base + lane] : 0;
    for (int j2 = 0; j2 < nn; j2++) {
      int sj = __shfl(s_l, j2, 64);
      const float* al = aint + (size_t)(base + j2) * NHEADS;
      const __bf16* hs = h + (size_t)sj * FDIM;
      #pragma unroll
      for (int j = 0; j < 5; j++)
        acc[j] += al[2 * j + hb] * (float)hs[lane + 64 * j];
    }
  }
  #pragma unroll
  for (int j = 0; j < 5; j++) {
    int c = lane + 64 * j;
    float rr = acc[j] + bias[c];
    out[(size_t)v * FDIM + c] = (__bf16)fmaxf(rr, 0.f);
  }
}

// ---------------- batch boundaries + pooling ----------------
__global__ void bstart_kernel(const int* __restrict__ batch, int* __restrict__ bstart,
                              int n, int B_) {
  int v = blockIdx.x * 256 + threadIdx.x;
  if (v > n) return;
  int bv = (v < n) ? batch[v] : B_;
  int bp = (v == 0) ? -1 : batch[v - 1];
  for (int gg = bp + 1; gg <= bv; gg++) bstart[gg] = v;
}

__global__ void pool_kernel(const __bf16* __restrict__ xin, const int* __restrict__ bstart,
                            float* __restrict__ g) {
  int gid = blockIdx.x;
  int c = blockIdx.y * 64 + threadIdx.x;
  int s = bstart[gid], e = bstart[gid + 1];
  float mx = -__builtin_inff(), sm = 0.f;
  for (int v = s; v < e; v++) {
    float val = (float)xin[(size_t)v * FDIM + c];
    mx = fmaxf(mx, val);
    sm += val;
  }
  float cntf = (float)(e - s);
  g[gid * (2 * FDIM) + c] = mx;
  g[gid * (2 * FDIM) + FDIM + c] = sm / fmaxf(cntf, 1.f);
}

// ---------------- launch ----------------
extern "C" void kernel_launch(void* const* d_in, const int* in_sizes, int n_in,
                              void* d_out, int out_size, void* d_ws, size_t ws_size,
                              hipStream_t stream)
{
  const int N = in_sizes[0] / FDIM;
  const int E = in_sizes[2] / 2;
  const int NB = (N + 255) / 256;

  const float* x[2]   = {(const float*)d_in[0], (const float*)d_in[1]};
  const int*   ei[2]  = {(const int*)d_in[2], (const int*)d_in[3]};
  const int*   bat[2] = {(const int*)d_in[4], (const int*)d_in[5]};
  const float* W_gcn   = (const float*)d_in[6];
  const float* b_gcn   = (const float*)d_in[7];
  const float* W_gat   = (const float*)d_in[8];
  const float* att_src = (const float*)d_in[9];
  const float* att_dst = (const float*)d_in[10];
  const float* b_gat   = (const float*)d_in[11];
  const float* W_fc_g1 = (const float*)d_in[12];
  const float* b_fc_g1 = (const float*)d_in[13];
  const float* W_fc_g2 = (const float*)d_in[14];
  const float* b_fc_g2 = (const float*)d_in[15];
  const float* W_fc1   = (const float*)d_in[16];
  const float* b_fc1   = (const float*)d_in[17];
  const float* W_fc2   = (const float*)d_in[18];
  const float* b_fc2   = (const float*)d_in[19];
  const float* W_out   = (const float*)d_in[20];
  const float* b_out   = (const float*)d_in[21];
  float* outp = (float*)d_out;

  char* ws = (char*)d_ws;
  size_t off = 0;
  auto alloc = [&](size_t bytes) -> char* {
    char* p = ws + off;
    off += (bytes + 255) & ~(size_t)255;
    return p;
  };
  int*    cnt    = (int*)alloc((size_t)N * 4);
  int*    fil    = (int*)alloc((size_t)N * 4);
  size_t  zero_span = (size_t)((char*)fil - (char*)cnt) + ((size_t)N * 4 + 255 & ~(size_t)255);
  int*    rp     = (int*)alloc((size_t)(N + 1) * 4);
  int*    bsum   = (int*)alloc((size_t)NB * 4);
  int*    csr    = (int*)alloc((size_t)E * 4);
  int*    csrd   = (int*)alloc((size_t)E * 4);
  float*  dinv   = (float*)alloc((size_t)N * 4);
  int*    bstart = (int*)alloc((size_t)(NGR + 1) * 4);
  __bf16* WgcnT  = (__bf16*)alloc((size_t)FDIM * FDIM * 2);
  __bf16* WgatT  = (__bf16*)alloc((size_t)FDIM * FDIM * 2);
  __bf16* hbuf   = (__bf16*)alloc((size_t)N * FDIM * 2);
  __bf16* xbuf   = (__bf16*)alloc((size_t)N * FDIM * 2);
  float*  as_    = (float*)alloc((size_t)N * NHEADS * 4);
  float*  ad_    = (float*)alloc((size_t)N * NHEADS * 4);
  float*  es     = (float*)alloc((size_t)E * NHEADS * 4);
  float*  aint   = (float*)alloc((size_t)E * NHEADS * 4);
  float*  mseg   = (float*)alloc((size_t)N * NHEADS * 4);
  float*  invden = (float*)alloc((size_t)N * NHEADS * 4);
  float*  aself  = (float*)alloc((size_t)N * NHEADS * 4);
  float*  g      = (float*)alloc((size_t)2 * NGR * 2 * FDIM * 4);   // both branches
  float*  t1     = (float*)alloc((size_t)2 * NGR * 1500 * 4);       // both branches
  float*  xc     = (float*)alloc((size_t)NGR * 256 * 4);
  float*  t2     = (float*)alloc((size_t)NGR * 1024 * 4);
  float*  t3     = (float*)alloc((size_t)NGR * 512 * 4);
  float*  part   = (float*)alloc((size_t)8 * 512 * 512 * 4);        // split-K partials (8 MB)
  if (off > ws_size) return;  // workspace too small: bail (visible as absmax fail)

  wconv_kernel<<<(FDIM * FDIM) / 256, 256, 0, stream>>>(W_gcn, WgcnT);
  wconv_kernel<<<(FDIM * FDIM) / 256, 256, 0, stream>>>(W_gat, WgatT);

  for (int br = 0; br < 2; br++) {
    hipMemsetAsync(cnt, 0, zero_span, stream);
    const int* srcp = ei[br];
    const int* dstp = ei[br] + E;
    count_kernel<<<(E + 255) / 256, 256, 0, stream>>>(dstp, cnt, E);
    bsum_kernel<<<NB, 256, 0, stream>>>(cnt, bsum, N);
    bscan_kernel<<<1, 256, 0, stream>>>(bsum, NB);
    rpfill_kernel<<<NB, 256, 0, stream>>>(cnt, bsum, rp, dinv, N, E);
    fill_kernel<<<(E + 255) / 256, 256, 0, stream>>>(srcp, dstp, rp, fil, csr, csrd, E);

    dim3 g320((N + 63) / 64, 2);
    gemm320f_kernel<float><<<g320, 256, 0, stream>>>(x[br], WgcnT, hbuf, N);
    gcn_agg_kernel<<<(N + 3) / 4, 256, 0, stream>>>(hbuf, rp, csr, dinv, b_gcn, xbuf, N);
    gemm320f_kernel<__bf16><<<g320, 256, 0, stream>>>(xbuf, WgatT, hbuf, N);
    gat_scores_kernel<<<(N + 3) / 4, 256, 0, stream>>>(hbuf, att_src, att_dst, as_, ad_, N);

    escore_kernel<<<(E + 255) / 256, 256, 0, stream>>>(csr, csrd, as_, ad_, es, E);
    dim3 gmd(NB, NHEADS);
    mdenom_kernel<<<gmd, 256, 0, stream>>>(es, rp, as_, ad_, mseg, invden, aself, N, E);
    alpha_kernel<<<(E + 255) / 256, 256, 0, stream>>>(csrd, mseg, invden, es, aint, E);
    gat_agg_kernel<<<(N + 3) / 4, 256, 0, stream>>>(hbuf, rp, csr, aint, aself, b_gat, xbuf, N);

    bstart_kernel<<<(N + 256) / 256, 256, 0, stream>>>(bat[br], bstart, N, NGR);
    dim3 gpool(NGR, FDIM / 64);
    pool_kernel<<<gpool, 64, 0, stream>>>(xbuf, bstart, g + (size_t)br * NGR * 2 * FDIM);
  }

  // ---- batched FC head: M=512 covers both branches ----
  {
    dim3 gfc1((512 + BM - 1) / BM, (1500 + BN - 1) / BN);
    gemm_bf16_kernel<3><<<gfc1, 256, 0, stream>>>(g, W_fc_g1, t1, b_fc_g1, 512, 1500, 2 * FDIM, 1500);
    int S = 8, KS = ((1500 + S * BK - 1) / (S * BK)) * BK;
    dim3 gfc2((512 + BM - 1) / BM, (128 + BN - 1) / BN, S);
    gemm_splitk_kernel<<<gfc2, 256, 0, stream>>>(t1, W_fc_g2, part, 512, 128, 1500, KS);
    reduce_kernel<2, true><<<(512 * 128 + 255) / 256, 256, 0, stream>>>(part, xc, b_fc_g2, 512, 128, S, 256);
  }
  {
    dim3 gx1((NGR + BM - 1) / BM, (1024 + BN - 1) / BN);
    gemm_bf16_kernel<3><<<gx1, 256, 0, stream>>>(xc, W_fc1, t2, b_fc1, NGR, 1024, 256, 1024);
    int S = 4, KS = ((1024 + S * BK - 1) / (S * BK)) * BK;
    dim3 gx2((NGR + BM - 1) / BM, (512 + BN - 1) / BN, S);
    gemm_splitk_kernel<<<gx2, 256, 0, stream>>>(t2, W_fc2, part, NGR, 512, 1024, KS);
    reduce_kernel<3, false><<<(NGR * 512 + 255) / 256, 256, 0, stream>>>(part, t3, b_fc2, NGR, 512, S, 512);
    int S2 = 4, KS2 = ((512 + S2 * BK - 1) / (S2 * BK)) * BK;
    dim3 gx3((NGR + BM - 1) / BM, 1, S2);
    gemm_splitk_kernel<<<gx3, 256, 0, stream>>>(t3, W_out, part, NGR, 2, 512, KS2);
    reduce_kernel<2, false><<<(NGR * 2 + 255) / 256, 256, 0, stream>>>(part, outp, b_out, NGR, 2, S2, 2);
  }
}

// Round 7
// 818.684 us; speedup vs baseline: 1.1022x; 1.1022x over previous
//
#include <hip/hip_runtime.h>
#include <type_traits>

#define FDIM 320
#define NHEADS 10
#define NGR 256

typedef __bf16 bf16x8 __attribute__((ext_vector_type(8)));
typedef float f32x4 __attribute__((ext_vector_type(4)));

// ---------------- weight transpose+convert: Wt[c*320+k] = (bf16)W[k*320+c] --
__global__ void wconv_kernel(const float* __restrict__ W, __bf16* __restrict__ Wt) {
  int idx = blockIdx.x * 256 + threadIdx.x;
  int k = idx / FDIM, c = idx - k * FDIM;
  Wt[c * FDIM + k] = (__bf16)W[idx];
}

// ---------------- node GEMM v3: full-N, BK=32, LDS dbuf, async reg-stage ---
// C[M,320] = A[M,320] * W[320,320]. Block: 64 rows x full 320 cols.
// Per K-step: issue next-step global loads -> compute(cur) -> ds_write(nxt)
// -> ONE barrier. A fetched exactly once per dispatch.
#define GLSTR 40   // LDS row stride elems (80B)

template<typename TA>
__global__ __launch_bounds__(256, 2) void gemm320v3_kernel(
    const TA* __restrict__ A, const __bf16* __restrict__ Wt,
    __bf16* __restrict__ C, int M)
{
  __shared__ __bf16 As[2][64 * GLSTR];    // 2 x 5,120 B
  __shared__ __bf16 Bs[2][320 * GLSTR];   // 2 x 25,600 B  (total 61,440 B)

  const int tid = threadIdx.x;
  const int lane = tid & 63;
  const int w = tid >> 6;
  const int wr = w >> 1, wc = w & 1;      // wave: 32 rows x 160 cols
  const int r = lane & 15, kg = lane >> 4;
  const int m0 = blockIdx.x * 64;

  // staging thread assignments
  const int brow = tid >> 2, bq = tid & 3;      // A: row, 8-elem quarter
  const int gmrow = m0 + brow;
  const bool arow_ok = gmrow < M;

  bf16x8 bstg[5];          // B staged chunks (5 x 16B)
  bf16x8 astg;             // A staged (bf16 path)
  float4 af32a, af32b;     // A staged (f32 path)

  // ---- load step k into regs ----
  auto stage_load = [&](int k0) {
    #pragma unroll
    for (int i = 0; i < 5; i++) {
      int ch = tid + i * 256;
      int col = ch >> 2, kc = ch & 3;
      bstg[i] = *(const bf16x8*)(Wt + (size_t)col * FDIM + k0 + kc * 8);
    }
    if constexpr (std::is_same_v<TA, float>) {
      if (arow_ok) {
        const float4* ap = (const float4*)(A + (size_t)gmrow * FDIM + k0 + bq * 8);
        af32a = ap[0]; af32b = ap[1];
      }
    } else {
      if (arow_ok) astg = *(const bf16x8*)(A + (size_t)gmrow * FDIM + k0 + bq * 8);
    }
  };
  // ---- write staged regs into LDS buffer b ----
  auto stage_write = [&](int b) {
    #pragma unroll
    for (int i = 0; i < 5; i++) {
      int ch = tid + i * 256;
      int col = ch >> 2, kc = ch & 3;
      *(bf16x8*)&Bs[b][col * GLSTR + kc * 8] = bstg[i];
    }
    bf16x8 v = {};
    if constexpr (std::is_same_v<TA, float>) {
      if (arow_ok) {
        v[0]=(__bf16)af32a.x; v[1]=(__bf16)af32a.y; v[2]=(__bf16)af32a.z; v[3]=(__bf16)af32a.w;
        v[4]=(__bf16)af32b.x; v[5]=(__bf16)af32b.y; v[6]=(__bf16)af32b.z; v[7]=(__bf16)af32b.w;
      }
    } else {
      if (arow_ok) v = astg;
    }
    *(bf16x8*)&As[b][brow * GLSTR + bq * 8] = v;
  };

  f32x4 acc0[10], acc1[10];
  #pragma unroll
  for (int i = 0; i < 10; i++) { acc0[i] = (f32x4){0,0,0,0}; acc1[i] = (f32x4){0,0,0,0}; }

  // prologue: fill buffer 0
  stage_load(0);
  stage_write(0);
  __syncthreads();

  int cur = 0;
  for (int k = 0; k < 10; k++) {
    if (k < 9) stage_load((k + 1) * 32);          // async: loads in flight during compute
    // ---- compute from buf cur ----
    {
      bf16x8 a0 = *(const bf16x8*)&As[cur][(wr*32 + r)      * GLSTR + kg*8];
      bf16x8 a1 = *(const bf16x8*)&As[cur][(wr*32 + 16 + r) * GLSTR + kg*8];
      #pragma unroll
      for (int nf = 0; nf < 10; nf++) {
        bf16x8 b = *(const bf16x8*)&Bs[cur][(wc*160 + nf*16 + r) * GLSTR + kg*8];
        acc0[nf] = __builtin_amdgcn_mfma_f32_16x16x32_bf16(a0, b, acc0[nf], 0, 0, 0);
        acc1[nf] = __builtin_amdgcn_mfma_f32_16x16x32_bf16(a1, b, acc1[nf], 0, 0, 0);
      }
    }
    if (k < 9) {
      stage_write(cur ^ 1);     // compiler inserts vmcnt before these ds_writes
      __syncthreads();          // nxt ready for all; cur free to overwrite next iter
      cur ^= 1;
    }
  }

  // ---- store ----
  #pragma unroll
  for (int nf = 0; nf < 10; nf++) {
    int gn = wc*160 + nf*16 + r;
    #pragma unroll
    for (int q = 0; q < 4; q++) {
      int gm0 = m0 + wr*32 + kg*4 + q;
      if (gm0 < M)       C[(size_t)gm0 * FDIM + gn] = (__bf16)acc0[nf][q];
      int gm1 = gm0 + 16;
      if (gm1 < M)       C[(size_t)gm1 * FDIM + gn] = (__bf16)acc1[nf][q];
    }
  }
}

// ---------------- generic GEMM (FC layers): C = A*B, f32 in/out ------------
#define BM 128
#define BN 64
#define BK 32
#define LSTR 56

template<int FLAGS>  // bit0: relu, bit1: bias
__global__ __launch_bounds__(256) void gemm_bf16_kernel(
    const float* __restrict__ A, const float* __restrict__ B,
    float* __restrict__ C, const float* __restrict__ bias,
    int M, int N, int K, int ldc)
{
  __shared__ __bf16 As[BM * LSTR];
  __shared__ __bf16 Bs[BN * LSTR];

  const int tid = threadIdx.x;
  const int lane = tid & 63;
  const int w = tid >> 6;
  const int wm = w >> 1, wn = w & 1;
  const int r = lane & 15, kg = lane >> 4;
  const int m0 = blockIdx.x * BM, n0 = blockIdx.y * BN;

  f32x4 acc[4][2];
  #pragma unroll
  for (int i = 0; i < 4; i++)
    #pragma unroll
    for (int j = 0; j < 2; j++)
      acc[i][j] = (f32x4){0.f, 0.f, 0.f, 0.f};

  const int arow = tid >> 1, ahalf = tid & 1;
  const int bk = tid >> 3, bn = (tid & 7) * 8;

  for (int k0 = 0; k0 < K; k0 += BK) {
    __syncthreads();
    {
      int gm = m0 + arow;
      int kbase = k0 + ahalf * 16;
      float tmp[16];
      if (gm < M && kbase + 16 <= K) {
        const float4* ap = (const float4*)(A + (size_t)gm * K + kbase);
        #pragma unroll
        for (int q = 0; q < 4; q++) {
          float4 v = ap[q];
          tmp[q*4+0] = v.x; tmp[q*4+1] = v.y; tmp[q*4+2] = v.z; tmp[q*4+3] = v.w;
        }
      } else {
        #pragma unroll
        for (int q = 0; q < 16; q++) {
          int kk = kbase + q;
          tmp[q] = (gm < M && kk < K) ? A[(size_t)gm * K + kk] : 0.f;
        }
      }
      bf16x8 v0, v1;
      #pragma unroll
      for (int q = 0; q < 8; q++) { v0[q] = (__bf16)tmp[q]; v1[q] = (__bf16)tmp[q+8]; }
      bf16x8* dp = (bf16x8*)&As[arow * LSTR + ahalf * 16];
      dp[0] = v0; dp[1] = v1;
    }
    {
      int gk = k0 + bk;
      float tb[8];
      if (gk < K && n0 + bn + 8 <= N) {
        const float4* bp = (const float4*)(B + (size_t)gk * N + n0 + bn);
        float4 u0 = bp[0], u1 = bp[1];
        tb[0]=u0.x; tb[1]=u0.y; tb[2]=u0.z; tb[3]=u0.w;
        tb[4]=u1.x; tb[5]=u1.y; tb[6]=u1.z; tb[7]=u1.w;
      } else {
        #pragma unroll
        for (int q = 0; q < 8; q++) {
          int gn = n0 + bn + q;
          tb[q] = (gk < K && gn < N) ? B[(size_t)gk * N + gn] : 0.f;
        }
      }
      #pragma unroll
      for (int q = 0; q < 8; q++) Bs[(bn + q) * LSTR + bk] = (__bf16)tb[q];
    }
    __syncthreads();
    bf16x8 af[4], bfr[2];
    #pragma unroll
    for (int mf = 0; mf < 4; mf++)
      af[mf] = *(const bf16x8*)&As[(wm*64 + mf*16 + r) * LSTR + kg*8];
    #pragma unroll
    for (int nf = 0; nf < 2; nf++)
      bfr[nf] = *(const bf16x8*)&Bs[(wn*32 + nf*16 + r) * LSTR + kg*8];
    #pragma unroll
    for (int mf = 0; mf < 4; mf++)
      #pragma unroll
      for (int nf = 0; nf < 2; nf++)
        acc[mf][nf] = __builtin_amdgcn_mfma_f32_16x16x32_bf16(af[mf], bfr[nf], acc[mf][nf], 0, 0, 0);
  }

  #pragma unroll
  for (int mf = 0; mf < 4; mf++) {
    #pragma unroll
    for (int nf = 0; nf < 2; nf++) {
      #pragma unroll
      for (int q = 0; q < 4; q++) {
        int gm = m0 + wm*64 + mf*16 + kg*4 + q;
        int gn = n0 + wn*32 + nf*16 + r;
        if (gm < M && gn < N) {
          float v = acc[mf][nf][q];
          if (FLAGS & 2) v += bias[gn];
          if (FLAGS & 1) v = fmaxf(v, 0.f);
          C[(size_t)gm * ldc + gn] = v;
        }
      }
    }
  }
}

// ---------------- split-K GEMM: P[s][M][N] partials ----------------
__global__ __launch_bounds__(256) void gemm_splitk_kernel(
    const float* __restrict__ A, const float* __restrict__ B,
    float* __restrict__ P, int M, int N, int K, int KS)
{
  __shared__ __bf16 As[BM * LSTR];
  __shared__ __bf16 Bs[BN * LSTR];

  const int tid = threadIdx.x;
  const int lane = tid & 63;
  const int w = tid >> 6;
  const int wm = w >> 1, wn = w & 1;
  const int r = lane & 15, kg = lane >> 4;
  const int m0 = blockIdx.x * BM, n0 = blockIdx.y * BN;
  const int kstart = blockIdx.z * KS;
  const int kend = min(K, kstart + KS);

  f32x4 acc[4][2];
  #pragma unroll
  for (int i = 0; i < 4; i++)
    #pragma unroll
    for (int j = 0; j < 2; j++)
      acc[i][j] = (f32x4){0.f, 0.f, 0.f, 0.f};

  const int arow = tid >> 1, ahalf = tid & 1;
  const int bk = tid >> 3, bn = (tid & 7) * 8;

  for (int k0 = kstart; k0 < kend; k0 += BK) {
    __syncthreads();
    {
      int gm = m0 + arow;
      int kbase = k0 + ahalf * 16;
      float tmp[16];
      if (gm < M && kbase + 16 <= kend) {
        const float4* ap = (const float4*)(A + (size_t)gm * K + kbase);
        #pragma unroll
        for (int q = 0; q < 4; q++) {
          float4 v = ap[q];
          tmp[q*4+0] = v.x; tmp[q*4+1] = v.y; tmp[q*4+2] = v.z; tmp[q*4+3] = v.w;
        }
      } else {
        #pragma unroll
        for (int q = 0; q < 16; q++) {
          int kk = kbase + q;
          tmp[q] = (gm < M && kk < kend) ? A[(size_t)gm * K + kk] : 0.f;
        }
      }
      bf16x8 v0, v1;
      #pragma unroll
      for (int q = 0; q < 8; q++) { v0[q] = (__bf16)tmp[q]; v1[q] = (__bf16)tmp[q+8]; }
      bf16x8* dp = (bf16x8*)&As[arow * LSTR + ahalf * 16];
      dp[0] = v0; dp[1] = v1;
    }
    {
      int gk = k0 + bk;
      float tb[8];
      if (gk < kend && n0 + bn + 8 <= N) {
        const float4* bp = (const float4*)(B + (size_t)gk * N + n0 + bn);
        float4 u0 = bp[0], u1 = bp[1];
        tb[0]=u0.x; tb[1]=u0.y; tb[2]=u0.z; tb[3]=u0.w;
        tb[4]=u1.x; tb[5]=u1.y; tb[6]=u1.z; tb[7]=u1.w;
      } else {
        #pragma unroll
        for (int q = 0; q < 8; q++) {
          int gn = n0 + bn + q;
          tb[q] = (gk < kend && gn < N) ? B[(size_t)gk * N + gn] : 0.f;
        }
      }
      #pragma unroll
      for (int q = 0; q < 8; q++) Bs[(bn + q) * LSTR + bk] = (__bf16)tb[q];
    }
    __syncthreads();
    bf16x8 af[4], bfr[2];
    #pragma unroll
    for (int mf = 0; mf < 4; mf++)
      af[mf] = *(const bf16x8*)&As[(wm*64 + mf*16 + r) * LSTR + kg*8];
    #pragma unroll
    for (int nf = 0; nf < 2; nf++)
      bfr[nf] = *(const bf16x8*)&Bs[(wn*32 + nf*16 + r) * LSTR + kg*8];
    #pragma unroll
    for (int mf = 0; mf < 4; mf++)
      #pragma unroll
      for (int nf = 0; nf < 2; nf++)
        acc[mf][nf] = __builtin_amdgcn_mfma_f32_16x16x32_bf16(af[mf], bfr[nf], acc[mf][nf], 0, 0, 0);
  }

  float* Pp = P + (size_t)blockIdx.z * M * N;
  #pragma unroll
  for (int mf = 0; mf < 4; mf++) {
    #pragma unroll
    for (int nf = 0; nf < 2; nf++) {
      #pragma unroll
      for (int q = 0; q < 4; q++) {
        int gm = m0 + wm*64 + mf*16 + kg*4 + q;
        int gn = n0 + wn*32 + nf*16 + r;
        if (gm < M && gn < N)
          Pp[(size_t)gm * N + gn] = acc[mf][nf][q];
      }
    }
  }
}

// reduce partials; STACK: rows M/2.. go to cols N.. (fc_g2 branch packing)
template<int FLAGS, bool STACK>
__global__ void reduce_kernel(const float* __restrict__ P, float* __restrict__ C,
                              const float* __restrict__ bias, int M, int N, int S, int ldc)
{
  int i = blockIdx.x * 256 + threadIdx.x;
  if (i >= M * N) return;
  float v = 0.f;
  for (int s = 0; s < S; s++) v += P[(size_t)s * M * N + i];
  int row = i / N, col = i - row * N;
  if (FLAGS & 2) v += bias[col];
  if (FLAGS & 1) v = fmaxf(v, 0.f);
  if (STACK) { if (row >= (M >> 1)) { row -= (M >> 1); col += N; } }
  C[(size_t)row * ldc + col] = v;
}

// ---------------- CSR build ----------------
__global__ void count_kernel(const int* __restrict__ dst, int* __restrict__ cnt, int E) {
  int e = blockIdx.x * 256 + threadIdx.x;
  if (e < E) atomicAdd(&cnt[dst[e]], 1);
}

__global__ void bsum_kernel(const int* __restrict__ cnt, int* __restrict__ bsum, int n) {
  __shared__ int wp[4];
  int tid = threadIdx.x, lane = tid & 63, wid = tid >> 6;
  int i = blockIdx.x * 256 + tid;
  int v = (i < n) ? cnt[i] : 0;
  #pragma unroll
  for (int off = 32; off >= 1; off >>= 1) v += __shfl_xor(v, off, 64);
  if (lane == 0) wp[wid] = v;
  __syncthreads();
  if (tid == 0) bsum[blockIdx.x] = wp[0] + wp[1] + wp[2] + wp[3];
}

__global__ void bscan_kernel(int* __restrict__ bsum, int nb) {
  __shared__ int wp[4];
  int tid = threadIdx.x, lane = tid & 63, wid = tid >> 6;
  int v = (tid < nb) ? bsum[tid] : 0;
  int xv = v;
  #pragma unroll
  for (int off = 1; off < 64; off <<= 1) {
    int y = __shfl_up(xv, off, 64);
    if (lane >= off) xv += y;
  }
  if (lane == 63) wp[wid] = xv;
  __syncthreads();
  if (tid == 0) { int s = 0; for (int k = 0; k < 4; k++) { int t = wp[k]; wp[k] = s; s += t; } }
  __syncthreads();
  if (tid < nb) bsum[tid] = wp[wid] + xv - v;   // exclusive
}

__global__ void rpfill_kernel(const int* __restrict__ cnt, const int* __restrict__ bsum,
                              int* __restrict__ rp, float* __restrict__ dinv, int n, int E) {
  __shared__ int wp[4];
  int tid = threadIdx.x, lane = tid & 63, wid = tid >> 6;
  int i = blockIdx.x * 256 + tid;
  int v = (i < n) ? cnt[i] : 0;
  int xv = v;
  #pragma unroll
  for (int off = 1; off < 64; off <<= 1) {
    int y = __shfl_up(xv, off, 64);
    if (lane >= off) xv += y;
  }
  if (lane == 63) wp[wid] = xv;
  __syncthreads();
  if (tid == 0) { int s = 0; for (int k = 0; k < 4; k++) { int t = wp[k]; wp[k] = s; s += t; } }
  __syncthreads();
  if (i < n) {
    rp[i] = bsum[blockIdx.x] + wp[wid] + xv - v;
    dinv[i] = rsqrtf((float)(v + 1));
  }
  if (blockIdx.x == 0 && tid == 0) rp[n] = E;
}

__global__ void fill_kernel(const int* __restrict__ src, const int* __restrict__ dst,
                            const int* __restrict__ rp, int* __restrict__ fil,
                            int* __restrict__ csr, int* __restrict__ csr_dst, int E) {
  int e = blockIdx.x * 256 + threadIdx.x;
  if (e < E) {
    int d = dst[e];
    int pos = rp[d] + atomicAdd(&fil[d], 1);
    csr[pos] = src[e];
    csr_dst[pos] = d;
  }
}

// ---------------- GCN aggregate (wave/node, chunked edge preload, bf16 h) --
__global__ void gcn_agg_kernel(const __bf16* __restrict__ h, const int* __restrict__ rp,
                               const int* __restrict__ csr, const float* __restrict__ dinv,
                               const float* __restrict__ bias, __bf16* __restrict__ out, int n)
{
  const int lane = threadIdx.x & 63;
  const int v = blockIdx.x * 4 + (threadIdx.x >> 6);
  if (v >= n) return;
  const float dv = dinv[v];
  const int e0 = rp[v], e1 = rp[v + 1];
  float acc[5];
  #pragma unroll
  for (int j = 0; j < 5; j++) acc[j] = dv * (float)h[(size_t)v * FDIM + lane + 64 * j];
  for (int base = e0; base < e1; base += 64) {
    int nn = min(64, e1 - base);
    int s_l = (lane < nn) ? csr[base + lane] : 0;
    float d_l = (lane < nn) ? dinv[s_l] : 0.f;
    for (int j2 = 0; j2 < nn; j2++) {
      int sj = __shfl(s_l, j2, 64);
      float cj = __shfl(d_l, j2, 64);
      const __bf16* hs = h + (size_t)sj * FDIM;
      #pragma unroll
      for (int j = 0; j < 5; j++) acc[j] += cj * (float)hs[lane + 64 * j];
    }
  }
  #pragma unroll
  for (int j = 0; j < 5; j++) {
    float rr = dv * acc[j] + bias[lane + 64 * j];
    out[(size_t)v * FDIM + lane + 64 * j] = (__bf16)fmaxf(rr, 0.f);
  }
}

// ---------------- GAT attention scores a_s, a_d (one wave per node) --------
__global__ void gat_scores_kernel(const __bf16* __restrict__ h, const float* __restrict__ att_s,
                                  const float* __restrict__ att_d, float* __restrict__ as_,
                                  float* __restrict__ ad_, int n)
{
  const int lane = threadIdx.x & 63;
  const int v = blockIdx.x * 4 + (threadIdx.x >> 6);
  if (v >= n) return;
  const int c = lane & 31;
  const int hh = lane >> 5;
  #pragma unroll
  for (int j = 0; j < 5; j++) {
    int head = hh * 5 + j;
    float xv = (float)h[(size_t)v * FDIM + head * 32 + c];
    float ps = xv * att_s[head * 32 + c];
    float pd = xv * att_d[head * 32 + c];
    #pragma unroll
    for (int off = 1; off < 32; off <<= 1) {
      ps += __shfl_xor(ps, off, 64);
      pd += __shfl_xor(pd, off, 64);
    }
    if (c == 0) { as_[v * NHEADS + head] = ps; ad_[v * NHEADS + head] = pd; }
  }
}

__device__ __forceinline__ float lrelu(float x) { return x > 0.f ? x : 0.2f * x; }

// ---------------- edge-parallel raw scores, PLANE layout es[t*E + e] -------
__global__ void escore_kernel(const int* __restrict__ csr, const int* __restrict__ csr_dst,
                              const float* __restrict__ as_, const float* __restrict__ ad_,
                              float* __restrict__ es, int E)
{
  int i = blockIdx.x * 256 + threadIdx.x;
  if (i >= E) return;
  int s = csr[i], d = csr_dst[i];
  const float* ap = as_ + (size_t)s * NHEADS;
  const float* dp = ad_ + (size_t)d * NHEADS;
  #pragma unroll
  for (int t = 0; t < NHEADS; t++) es[(size_t)t * E + i] = lrelu(ap[t] + dp[t]);
}

// ---------------- per-(node,head) segment max + denom; head = blockIdx.y ---
__global__ void mdenom_kernel(const float* __restrict__ es, const int* __restrict__ rp,
                              const float* __restrict__ as_, const float* __restrict__ ad_,
                              float* __restrict__ mseg, float* __restrict__ invden,
                              float* __restrict__ aself, int n, int E)
{
  int v = blockIdx.x * 256 + threadIdx.x;
  if (v >= n) return;
  int t = blockIdx.y;
  int e0 = rp[v], e1 = rp[v + 1];
  float esf = lrelu(as_[v * NHEADS + t] + ad_[v * NHEADS + t]);
  const float* ep = es + (size_t)t * E;
  float m = esf;
  for (int e = e0; e < e1; e++) m = fmaxf(m, ep[e]);
  float den = __expf(esf - m);
  float pself = den;
  for (int e = e0; e < e1; e++) den += __expf(ep[e] - m);
  float inv = 1.f / den;
  mseg[v * NHEADS + t] = m;
  invden[v * NHEADS + t] = inv;
  aself[v * NHEADS + t] = pself * inv;
}

// ---------------- edge-parallel alpha: planes -> interleaved [e][10] -------
__global__ void alpha_kernel(const int* __restrict__ csr_dst, const float* __restrict__ mseg,
                             const float* __restrict__ invden, const float* __restrict__ es,
                             float* __restrict__ aint, int E)
{
  int i = blockIdx.x * 256 + threadIdx.x;
  if (i >= E) return;
  int d = csr_dst[i];
  const float* mp = mseg + (size_t)d * NHEADS;
  const float* ip = invden + (size_t)d * NHEADS;
  float* op = aint + (size_t)i * NHEADS;
  #pragma unroll
  for (int t = 0; t < NHEADS; t++)
    op[t] = __expf(es[(size_t)t * E + i] - mp[t]) * ip[t];
}

// ---------------- GAT aggregate (wave/node, interleaved alpha, bf16 h) -----
__global__ void gat_agg_kernel(const __bf16* __restrict__ h, const int* __restrict__ rp,
                               const int* __restrict__ csr, const float* __restrict__ aint,
                               const float* __restrict__ aself, const float* __restrict__ bias,
                               __bf16* __restrict__ out, int n)
{
  const int lane = threadIdx.x & 63;
  const int v = blockIdx.x * 4 + (threadIdx.x >> 6);
  if (v >= n) return;
  const int hb = lane >> 5;   // head of channel lane+64j is 2j+hb
  const int e0 = rp[v], e1 = rp[v + 1];
  const float* asf = aself + (size_t)v * NHEADS;
  float acc[5];
  #pragma unroll
  for (int j = 0; j < 5; j++)
    acc[j] = asf[2 * j + hb] * (float)h[(size_t)v * FDIM + lane + 64 * j];
  for (int base = e0; base < e1; base += 64) {
    int nn = min(64, e1 - base);
    int s_l = (lane < nn) ? csr[base + lane] : 0;
    for (int j2 = 0; j2 < nn; j2++) {
      int sj = __shfl(s_l, j2, 64);
      const float* al = aint + (size_t)(base + j2) * NHEADS;
      const __bf16* hs = h + (size_t)sj * FDIM;
      #pragma unroll
      for (int j = 0; j < 5; j++)
        acc[j] += al[2 * j + hb] * (float)hs[lane + 64 * j];
    }
  }
  #pragma unroll
  for (int j = 0; j < 5; j++) {
    int c = lane + 64 * j;
    float rr = acc[j] + bias[c];
    out[(size_t)v * FDIM + c] = (__bf16)fmaxf(rr, 0.f);
  }
}

// ---------------- batch boundaries + pooling ----------------
__global__ void bstart_kernel(const int* __restrict__ batch, int* __restrict__ bstart,
                              int n, int B_) {
  int v = blockIdx.x * 256 + threadIdx.x;
  if (v > n) return;
  int bv = (v < n) ? batch[v] : B_;
  int bp = (v == 0) ? -1 : batch[v - 1];
  for (int gg = bp + 1; gg <= bv; gg++) bstart[gg] = v;
}

__global__ void pool_kernel(const __bf16* __restrict__ xin, const int* __restrict__ bstart,
                            float* __restrict__ g) {
  int gid = blockIdx.x;
  int c = blockIdx.y * 64 + threadIdx.x;
  int s = bstart[gid], e = bstart[gid + 1];
  float mx = -__builtin_inff(), sm = 0.f;
  for (int v = s; v < e; v++) {
    float val = (float)xin[(size_t)v * FDIM + c];
    mx = fmaxf(mx, val);
    sm += val;
  }
  float cntf = (float)(e - s);
  g[gid * (2 * FDIM) + c] = mx;
  g[gid * (2 * FDIM) + FDIM + c] = sm / fmaxf(cntf, 1.f);
}

// ---------------- launch ----------------
extern "C" void kernel_launch(void* const* d_in, const int* in_sizes, int n_in,
                              void* d_out, int out_size, void* d_ws, size_t ws_size,
                              hipStream_t stream)
{
  const int N = in_sizes[0] / FDIM;
  const int E = in_sizes[2] / 2;
  const int NB = (N + 255) / 256;

  const float* x[2]   = {(const float*)d_in[0], (const float*)d_in[1]};
  const int*   ei[2]  = {(const int*)d_in[2], (const int*)d_in[3]};
  const int*   bat[2] = {(const int*)d_in[4], (const int*)d_in[5]};
  const float* W_gcn   = (const float*)d_in[6];
  const float* b_gcn   = (const float*)d_in[7];
  const float* W_gat   = (const float*)d_in[8];
  const float* att_src = (const float*)d_in[9];
  const float* att_dst = (const float*)d_in[10];
  const float* b_gat   = (const float*)d_in[11];
  const float* W_fc_g1 = (const float*)d_in[12];
  const float* b_fc_g1 = (const float*)d_in[13];
  const float* W_fc_g2 = (const float*)d_in[14];
  const float* b_fc_g2 = (const float*)d_in[15];
  const float* W_fc1   = (const float*)d_in[16];
  const float* b_fc1   = (const float*)d_in[17];
  const float* W_fc2   = (const float*)d_in[18];
  const float* b_fc2   = (const float*)d_in[19];
  const float* W_out   = (const float*)d_in[20];
  const float* b_out   = (const float*)d_in[21];
  float* outp = (float*)d_out;

  char* ws = (char*)d_ws;
  size_t off = 0;
  auto alloc = [&](size_t bytes) -> char* {
    char* p = ws + off;
    off += (bytes + 255) & ~(size_t)255;
    return p;
  };
  int*    cnt    = (int*)alloc((size_t)N * 4);
  int*    fil    = (int*)alloc((size_t)N * 4);
  size_t  zero_span = (size_t)((char*)fil - (char*)cnt) + ((size_t)N * 4 + 255 & ~(size_t)255);
  int*    rp     = (int*)alloc((size_t)(N + 1) * 4);
  int*    bsum   = (int*)alloc((size_t)NB * 4);
  int*    csr    = (int*)alloc((size_t)E * 4);
  int*    csrd   = (int*)alloc((size_t)E * 4);
  float*  dinv   = (float*)alloc((size_t)N * 4);
  int*    bstart = (int*)alloc((size_t)(NGR + 1) * 4);
  __bf16* WgcnT  = (__bf16*)alloc((size_t)FDIM * FDIM * 2);
  __bf16* WgatT  = (__bf16*)alloc((size_t)FDIM * FDIM * 2);
  __bf16* hbuf   = (__bf16*)alloc((size_t)N * FDIM * 2);
  __bf16* xbuf   = (__bf16*)alloc((size_t)N * FDIM * 2);
  float*  as_    = (float*)alloc((size_t)N * NHEADS * 4);
  float*  ad_    = (float*)alloc((size_t)N * NHEADS * 4);
  float*  es     = (float*)alloc((size_t)E * NHEADS * 4);
  float*  aint   = (float*)alloc((size_t)E * NHEADS * 4);
  float*  mseg   = (float*)alloc((size_t)N * NHEADS * 4);
  float*  invden = (float*)alloc((size_t)N * NHEADS * 4);
  float*  aself  = (float*)alloc((size_t)N * NHEADS * 4);
  float*  g      = (float*)alloc((size_t)2 * NGR * 2 * FDIM * 4);   // both branches
  float*  t1     = (float*)alloc((size_t)2 * NGR * 1500 * 4);       // both branches
  float*  xc     = (float*)alloc((size_t)NGR * 256 * 4);
  float*  t2     = (float*)alloc((size_t)NGR * 1024 * 4);
  float*  t3     = (float*)alloc((size_t)NGR * 512 * 4);
  float*  part   = (float*)alloc((size_t)8 * 512 * 512 * 4);        // split-K partials (8 MB)
  if (off > ws_size) return;  // workspace too small: bail (visible as absmax fail)

  wconv_kernel<<<(FDIM * FDIM) / 256, 256, 0, stream>>>(W_gcn, WgcnT);
  wconv_kernel<<<(FDIM * FDIM) / 256, 256, 0, stream>>>(W_gat, WgatT);

  for (int br = 0; br < 2; br++) {
    hipMemsetAsync(cnt, 0, zero_span, stream);
    const int* srcp = ei[br];
    const int* dstp = ei[br] + E;
    count_kernel<<<(E + 255) / 256, 256, 0, stream>>>(dstp, cnt, E);
    bsum_kernel<<<NB, 256, 0, stream>>>(cnt, bsum, N);
    bscan_kernel<<<1, 256, 0, stream>>>(bsum, NB);
    rpfill_kernel<<<NB, 256, 0, stream>>>(cnt, bsum, rp, dinv, N, E);
    fill_kernel<<<(E + 255) / 256, 256, 0, stream>>>(srcp, dstp, rp, fil, csr, csrd, E);

    int g320 = (N + 63) / 64;
    gemm320v3_kernel<float><<<g320, 256, 0, stream>>>(x[br], WgcnT, hbuf, N);
    gcn_agg_kernel<<<(N + 3) / 4, 256, 0, stream>>>(hbuf, rp, csr, dinv, b_gcn, xbuf, N);
    gemm320v3_kernel<__bf16><<<g320, 256, 0, stream>>>(xbuf, WgatT, hbuf, N);
    gat_scores_kernel<<<(N + 3) / 4, 256, 0, stream>>>(hbuf, att_src, att_dst, as_, ad_, N);

    escore_kernel<<<(E + 255) / 256, 256, 0, stream>>>(csr, csrd, as_, ad_, es, E);
    dim3 gmd(NB, NHEADS);
    mdenom_kernel<<<gmd, 256, 0, stream>>>(es, rp, as_, ad_, mseg, invden, aself, N, E);
    alpha_kernel<<<(E + 255) / 256, 256, 0, stream>>>(csrd, mseg, invden, es, aint, E);
    gat_agg_kernel<<<(N + 3) / 4, 256, 0, stream>>>(hbuf, rp, csr, aint, aself, b_gat, xbuf, N);

    bstart_kernel<<<(N + 256) / 256, 256, 0, stream>>>(bat[br], bstart, N, NGR);
    dim3 gpool(NGR, FDIM / 64);
    pool_kernel<<<gpool, 64, 0, stream>>>(xbuf, bstart, g + (size_t)br * NGR * 2 * FDIM);
  }

  // ---- batched FC head: M=512 covers both branches ----
  {
    dim3 gfc1((512 + BM - 1) / BM, (1500 + BN - 1) / BN);
    gemm_bf16_kernel<3><<<gfc1, 256, 0, stream>>>(g, W_fc_g1, t1, b_fc_g1, 512, 1500, 2 * FDIM, 1500);
    int S = 8, KS = ((1500 + S * BK - 1) / (S * BK)) * BK;
    dim3 gfc2((512 + BM - 1) / BM, (128 + BN - 1) / BN, S);
    gemm_splitk_kernel<<<gfc2, 256, 0, stream>>>(t1, W_fc_g2, part, 512, 128, 1500, KS);
    reduce_kernel<2, true><<<(512 * 128 + 255) / 256, 256, 0, stream>>>(part, xc, b_fc_g2, 512, 128, S, 256);
  }
  {
    dim3 gx1((NGR + BM - 1) / BM, (1024 + BN - 1) / BN);
    gemm_bf16_kernel<3><<<gx1, 256, 0, stream>>>(xc, W_fc1, t2, b_fc1, NGR, 1024, 256, 1024);
    int S = 4, KS = ((1024 + S * BK - 1) / (S * BK)) * BK;
    dim3 gx2((NGR + BM - 1) / BM, (512 + BN - 1) / BN, S);
    gemm_splitk_kernel<<<gx2, 256, 0, stream>>>(t2, W_fc2, part, NGR, 512, 1024, KS);
    reduce_kernel<3, false><<<(NGR * 512 + 255) / 256, 256, 0, stream>>>(part, t3, b_fc2, NGR, 512, S, 512);
    int S2 = 4, KS2 = ((512 + S2 * BK - 1) / (S2 * BK)) * BK;
    dim3 gx3((NGR + BM - 1) / BM, 1, S2);
    gemm_splitk_kernel<<<gx3, 256, 0, stream>>>(t3, W_out, part, NGR, 2, 512, KS2);
    reduce_kernel<2, false><<<(NGR * 2 + 255) / 256, 256, 0, stream>>>(part, outp, b_out, NGR, 2, S2, 2);
  }
}

// Round 8
// 754.224 us; speedup vs baseline: 1.1964x; 1.0855x over previous
//
#include <hip/hip_runtime.h>
#include <type_traits>

#define FDIM 320
#define NHEADS 10
#define NGR 256

typedef __bf16 bf16x8 __attribute__((ext_vector_type(8)));
typedef float f32x4 __attribute__((ext_vector_type(4)));

// ---------------- weight transpose+convert: Wt[c*320+k] = (bf16)W[k*320+c] --
__global__ void wconv_kernel(const float* __restrict__ W, __bf16* __restrict__ Wt) {
  int idx = blockIdx.x * 256 + threadIdx.x;
  int k = idx / FDIM, c = idx - k * FDIM;
  Wt[c * FDIM + k] = (__bf16)W[idx];
}

// ---------------- node GEMM v3: full-N, BK=32, LDS dbuf, async reg-stage ---
// C[M,320] = A[M,320] * W[320,320]. Optional fused GAT score epilogue:
// as_[v][t] = sum_c h[v][t*32+c]*att_s[t][c]  (from f32 acc, pre-rounding).
#define GLSTR 40   // LDS row stride elems (80B)

template<typename TA, bool SCORES>
__global__ __launch_bounds__(256, 2) void gemm320v3_kernel(
    const TA* __restrict__ A, const __bf16* __restrict__ Wt,
    __bf16* __restrict__ C, int M,
    const float* __restrict__ att_s, const float* __restrict__ att_d,
    float* __restrict__ as_, float* __restrict__ ad_)
{
  __shared__ __bf16 As[2][64 * GLSTR];
  __shared__ __bf16 Bs[2][320 * GLSTR];

  const int tid = threadIdx.x;
  const int lane = tid & 63;
  const int w = tid >> 6;
  const int wr = w >> 1, wc = w & 1;      // wave: 32 rows x 160 cols
  const int r = lane & 15, kg = lane >> 4;
  const int m0 = blockIdx.x * 64;

  const int brow = tid >> 2, bq = tid & 3;
  const int gmrow = m0 + brow;
  const bool arow_ok = gmrow < M;

  bf16x8 bstg[5];
  bf16x8 astg;
  float4 af32a, af32b;

  auto stage_load = [&](int k0) {
    #pragma unroll
    for (int i = 0; i < 5; i++) {
      int ch = tid + i * 256;
      int col = ch >> 2, kc = ch & 3;
      bstg[i] = *(const bf16x8*)(Wt + (size_t)col * FDIM + k0 + kc * 8);
    }
    if constexpr (std::is_same_v<TA, float>) {
      if (arow_ok) {
        const float4* ap = (const float4*)(A + (size_t)gmrow * FDIM + k0 + bq * 8);
        af32a = ap[0]; af32b = ap[1];
      }
    } else {
      if (arow_ok) astg = *(const bf16x8*)(A + (size_t)gmrow * FDIM + k0 + bq * 8);
    }
  };
  auto stage_write = [&](int b) {
    #pragma unroll
    for (int i = 0; i < 5; i++) {
      int ch = tid + i * 256;
      int col = ch >> 2, kc = ch & 3;
      *(bf16x8*)&Bs[b][col * GLSTR + kc * 8] = bstg[i];
    }
    bf16x8 v = {};
    if constexpr (std::is_same_v<TA, float>) {
      if (arow_ok) {
        v[0]=(__bf16)af32a.x; v[1]=(__bf16)af32a.y; v[2]=(__bf16)af32a.z; v[3]=(__bf16)af32a.w;
        v[4]=(__bf16)af32b.x; v[5]=(__bf16)af32b.y; v[6]=(__bf16)af32b.z; v[7]=(__bf16)af32b.w;
      }
    } else {
      if (arow_ok) v = astg;
    }
    *(bf16x8*)&As[b][brow * GLSTR + bq * 8] = v;
  };

  f32x4 acc0[10], acc1[10];
  #pragma unroll
  for (int i = 0; i < 10; i++) { acc0[i] = (f32x4){0,0,0,0}; acc1[i] = (f32x4){0,0,0,0}; }

  stage_load(0);
  stage_write(0);
  __syncthreads();

  int cur = 0;
  for (int k = 0; k < 10; k++) {
    if (k < 9) stage_load((k + 1) * 32);
    {
      bf16x8 a0 = *(const bf16x8*)&As[cur][(wr*32 + r)      * GLSTR + kg*8];
      bf16x8 a1 = *(const bf16x8*)&As[cur][(wr*32 + 16 + r) * GLSTR + kg*8];
      #pragma unroll
      for (int nf = 0; nf < 10; nf++) {
        bf16x8 b = *(const bf16x8*)&Bs[cur][(wc*160 + nf*16 + r) * GLSTR + kg*8];
        acc0[nf] = __builtin_amdgcn_mfma_f32_16x16x32_bf16(a0, b, acc0[nf], 0, 0, 0);
        acc1[nf] = __builtin_amdgcn_mfma_f32_16x16x32_bf16(a1, b, acc1[nf], 0, 0, 0);
      }
    }
    if (k < 9) {
      stage_write(cur ^ 1);
      __syncthreads();
      cur ^= 1;
    }
  }

  // ---- store C ----
  #pragma unroll
  for (int nf = 0; nf < 10; nf++) {
    int gn = wc*160 + nf*16 + r;
    #pragma unroll
    for (int q = 0; q < 4; q++) {
      int gm0 = m0 + wr*32 + kg*4 + q;
      if (gm0 < M)       C[(size_t)gm0 * FDIM + gn] = (__bf16)acc0[nf][q];
      int gm1 = gm0 + 16;
      if (gm1 < M)       C[(size_t)gm1 * FDIM + gn] = (__bf16)acc1[nf][q];
    }
  }

  // ---- fused GAT scores ----
  if constexpr (SCORES) {
    #pragma unroll
    for (int th = 0; th < 5; th++) {
      int t = wc * 5 + th;
      float s0 = att_s[t*32 + r],      s1 = att_s[t*32 + 16 + r];
      float d0 = att_d[t*32 + r],      d1 = att_d[t*32 + 16 + r];
      #pragma unroll
      for (int q = 0; q < 4; q++) {
        float ps0 = acc0[2*th][q]*s0 + acc0[2*th+1][q]*s1;
        float ps1 = acc1[2*th][q]*s0 + acc1[2*th+1][q]*s1;
        float pd0 = acc0[2*th][q]*d0 + acc0[2*th+1][q]*d1;
        float pd1 = acc1[2*th][q]*d0 + acc1[2*th+1][q]*d1;
        #pragma unroll
        for (int off = 1; off < 16; off <<= 1) {
          ps0 += __shfl_xor(ps0, off, 16);
          ps1 += __shfl_xor(ps1, off, 16);
          pd0 += __shfl_xor(pd0, off, 16);
          pd1 += __shfl_xor(pd1, off, 16);
        }
        if (r == 0) {
          int row0 = m0 + wr*32 + kg*4 + q;
          if (row0 < M) { as_[row0*NHEADS + t] = ps0; ad_[row0*NHEADS + t] = pd0; }
          int row1 = row0 + 16;
          if (row1 < M) { as_[row1*NHEADS + t] = ps1; ad_[row1*NHEADS + t] = pd1; }
        }
      }
    }
  }
}

// ---------------- generic GEMM (FC layers): C = A*B, f32 in/out ------------
#define BM 128
#define BN 64
#define BK 32
#define LSTR 56

template<int FLAGS>  // bit0: relu, bit1: bias
__global__ __launch_bounds__(256) void gemm_bf16_kernel(
    const float* __restrict__ A, const float* __restrict__ B,
    float* __restrict__ C, const float* __restrict__ bias,
    int M, int N, int K, int ldc)
{
  __shared__ __bf16 As[BM * LSTR];
  __shared__ __bf16 Bs[BN * LSTR];

  const int tid = threadIdx.x;
  const int lane = tid & 63;
  const int w = tid >> 6;
  const int wm = w >> 1, wn = w & 1;
  const int r = lane & 15, kg = lane >> 4;
  const int m0 = blockIdx.x * BM, n0 = blockIdx.y * BN;

  f32x4 acc[4][2];
  #pragma unroll
  for (int i = 0; i < 4; i++)
    #pragma unroll
    for (int j = 0; j < 2; j++)
      acc[i][j] = (f32x4){0.f, 0.f, 0.f, 0.f};

  const int arow = tid >> 1, ahalf = tid & 1;
  const int bk = tid >> 3, bn = (tid & 7) * 8;

  for (int k0 = 0; k0 < K; k0 += BK) {
    __syncthreads();
    {
      int gm = m0 + arow;
      int kbase = k0 + ahalf * 16;
      float tmp[16];
      if (gm < M && kbase + 16 <= K) {
        const float4* ap = (const float4*)(A + (size_t)gm * K + kbase);
        #pragma unroll
        for (int q = 0; q < 4; q++) {
          float4 v = ap[q];
          tmp[q*4+0] = v.x; tmp[q*4+1] = v.y; tmp[q*4+2] = v.z; tmp[q*4+3] = v.w;
        }
      } else {
        #pragma unroll
        for (int q = 0; q < 16; q++) {
          int kk = kbase + q;
          tmp[q] = (gm < M && kk < K) ? A[(size_t)gm * K + kk] : 0.f;
        }
      }
      bf16x8 v0, v1;
      #pragma unroll
      for (int q = 0; q < 8; q++) { v0[q] = (__bf16)tmp[q]; v1[q] = (__bf16)tmp[q+8]; }
      bf16x8* dp = (bf16x8*)&As[arow * LSTR + ahalf * 16];
      dp[0] = v0; dp[1] = v1;
    }
    {
      int gk = k0 + bk;
      float tb[8];
      if (gk < K && n0 + bn + 8 <= N) {
        const float4* bp = (const float4*)(B + (size_t)gk * N + n0 + bn);
        float4 u0 = bp[0], u1 = bp[1];
        tb[0]=u0.x; tb[1]=u0.y; tb[2]=u0.z; tb[3]=u0.w;
        tb[4]=u1.x; tb[5]=u1.y; tb[6]=u1.z; tb[7]=u1.w;
      } else {
        #pragma unroll
        for (int q = 0; q < 8; q++) {
          int gn = n0 + bn + q;
          tb[q] = (gk < K && gn < N) ? B[(size_t)gk * N + gn] : 0.f;
        }
      }
      #pragma unroll
      for (int q = 0; q < 8; q++) Bs[(bn + q) * LSTR + bk] = (__bf16)tb[q];
    }
    __syncthreads();
    bf16x8 af[4], bfr[2];
    #pragma unroll
    for (int mf = 0; mf < 4; mf++)
      af[mf] = *(const bf16x8*)&As[(wm*64 + mf*16 + r) * LSTR + kg*8];
    #pragma unroll
    for (int nf = 0; nf < 2; nf++)
      bfr[nf] = *(const bf16x8*)&Bs[(wn*32 + nf*16 + r) * LSTR + kg*8];
    #pragma unroll
    for (int mf = 0; mf < 4; mf++)
      #pragma unroll
      for (int nf = 0; nf < 2; nf++)
        acc[mf][nf] = __builtin_amdgcn_mfma_f32_16x16x32_bf16(af[mf], bfr[nf], acc[mf][nf], 0, 0, 0);
  }

  #pragma unroll
  for (int mf = 0; mf < 4; mf++) {
    #pragma unroll
    for (int nf = 0; nf < 2; nf++) {
      #pragma unroll
      for (int q = 0; q < 4; q++) {
        int gm = m0 + wm*64 + mf*16 + kg*4 + q;
        int gn = n0 + wn*32 + nf*16 + r;
        if (gm < M && gn < N) {
          float v = acc[mf][nf][q];
          if (FLAGS & 2) v += bias[gn];
          if (FLAGS & 1) v = fmaxf(v, 0.f);
          C[(size_t)gm * ldc + gn] = v;
        }
      }
    }
  }
}

// ---------------- split-K GEMM: P[s][M][N] partials ----------------
__global__ __launch_bounds__(256) void gemm_splitk_kernel(
    const float* __restrict__ A, const float* __restrict__ B,
    float* __restrict__ P, int M, int N, int K, int KS)
{
  __shared__ __bf16 As[BM * LSTR];
  __shared__ __bf16 Bs[BN * LSTR];

  const int tid = threadIdx.x;
  const int lane = tid & 63;
  const int w = tid >> 6;
  const int wm = w >> 1, wn = w & 1;
  const int r = lane & 15, kg = lane >> 4;
  const int m0 = blockIdx.x * BM, n0 = blockIdx.y * BN;
  const int kstart = blockIdx.z * KS;
  const int kend = min(K, kstart + KS);

  f32x4 acc[4][2];
  #pragma unroll
  for (int i = 0; i < 4; i++)
    #pragma unroll
    for (int j = 0; j < 2; j++)
      acc[i][j] = (f32x4){0.f, 0.f, 0.f, 0.f};

  const int arow = tid >> 1, ahalf = tid & 1;
  const int bk = tid >> 3, bn = (tid & 7) * 8;

  for (int k0 = kstart; k0 < kend; k0 += BK) {
    __syncthreads();
    {
      int gm = m0 + arow;
      int kbase = k0 + ahalf * 16;
      float tmp[16];
      if (gm < M && kbase + 16 <= kend) {
        const float4* ap = (const float4*)(A + (size_t)gm * K + kbase);
        #pragma unroll
        for (int q = 0; q < 4; q++) {
          float4 v = ap[q];
          tmp[q*4+0] = v.x; tmp[q*4+1] = v.y; tmp[q*4+2] = v.z; tmp[q*4+3] = v.w;
        }
      } else {
        #pragma unroll
        for (int q = 0; q < 16; q++) {
          int kk = kbase + q;
          tmp[q] = (gm < M && kk < kend) ? A[(size_t)gm * K + kk] : 0.f;
        }
      }
      bf16x8 v0, v1;
      #pragma unroll
      for (int q = 0; q < 8; q++) { v0[q] = (__bf16)tmp[q]; v1[q] = (__bf16)tmp[q+8]; }
      bf16x8* dp = (bf16x8*)&As[arow * LSTR + ahalf * 16];
      dp[0] = v0; dp[1] = v1;
    }
    {
      int gk = k0 + bk;
      float tb[8];
      if (gk < kend && n0 + bn + 8 <= N) {
        const float4* bp = (const float4*)(B + (size_t)gk * N + n0 + bn);
        float4 u0 = bp[0], u1 = bp[1];
        tb[0]=u0.x; tb[1]=u0.y; tb[2]=u0.z; tb[3]=u0.w;
        tb[4]=u1.x; tb[5]=u1.y; tb[6]=u1.z; tb[7]=u1.w;
      } else {
        #pragma unroll
        for (int q = 0; q < 8; q++) {
          int gn = n0 + bn + q;
          tb[q] = (gk < kend && gn < N) ? B[(size_t)gk * N + gn] : 0.f;
        }
      }
      #pragma unroll
      for (int q = 0; q < 8; q++) Bs[(bn + q) * LSTR + bk] = (__bf16)tb[q];
    }
    __syncthreads();
    bf16x8 af[4], bfr[2];
    #pragma unroll
    for (int mf = 0; mf < 4; mf++)
      af[mf] = *(const bf16x8*)&As[(wm*64 + mf*16 + r) * LSTR + kg*8];
    #pragma unroll
    for (int nf = 0; nf < 2; nf++)
      bfr[nf] = *(const bf16x8*)&Bs[(wn*32 + nf*16 + r) * LSTR + kg*8];
    #pragma unroll
    for (int mf = 0; mf < 4; mf++)
      #pragma unroll
      for (int nf = 0; nf < 2; nf++)
        acc[mf][nf] = __builtin_amdgcn_mfma_f32_16x16x32_bf16(af[mf], bfr[nf], acc[mf][nf], 0, 0, 0);
  }

  float* Pp = P + (size_t)blockIdx.z * M * N;
  #pragma unroll
  for (int mf = 0; mf < 4; mf++) {
    #pragma unroll
    for (int nf = 0; nf < 2; nf++) {
      #pragma unroll
      for (int q = 0; q < 4; q++) {
        int gm = m0 + wm*64 + mf*16 + kg*4 + q;
        int gn = n0 + wn*32 + nf*16 + r;
        if (gm < M && gn < N)
          Pp[(size_t)gm * N + gn] = acc[mf][nf][q];
      }
    }
  }
}

// reduce partials; STACK: rows M/2.. go to cols N.. (fc_g2 branch packing)
template<int FLAGS, bool STACK>
__global__ void reduce_kernel(const float* __restrict__ P, float* __restrict__ C,
                              const float* __restrict__ bias, int M, int N, int S, int ldc)
{
  int i = blockIdx.x * 256 + threadIdx.x;
  if (i >= M * N) return;
  float v = 0.f;
  for (int s = 0; s < S; s++) v += P[(size_t)s * M * N + i];
  int row = i / N, col = i - row * N;
  if (FLAGS & 2) v += bias[col];
  if (FLAGS & 1) v = fmaxf(v, 0.f);
  if (STACK) { if (row >= (M >> 1)) { row -= (M >> 1); col += N; } }
  C[(size_t)row * ldc + col] = v;
}

// ---------------- CSR build ----------------
__global__ void count_kernel(const int* __restrict__ dst, int* __restrict__ cnt, int E) {
  int e = blockIdx.x * 256 + threadIdx.x;
  if (e < E) atomicAdd(&cnt[dst[e]], 1);
}

__global__ void bsum_kernel(const int* __restrict__ cnt, int* __restrict__ bsum, int n) {
  __shared__ int wp[4];
  int tid = threadIdx.x, lane = tid & 63, wid = tid >> 6;
  int i = blockIdx.x * 256 + tid;
  int v = (i < n) ? cnt[i] : 0;
  #pragma unroll
  for (int off = 32; off >= 1; off >>= 1) v += __shfl_xor(v, off, 64);
  if (lane == 0) wp[wid] = v;
  __syncthreads();
  if (tid == 0) bsum[blockIdx.x] = wp[0] + wp[1] + wp[2] + wp[3];
}

__global__ void bscan_kernel(int* __restrict__ bsum, int nb) {
  __shared__ int wp[4];
  int tid = threadIdx.x, lane = tid & 63, wid = tid >> 6;
  int v = (tid < nb) ? bsum[tid] : 0;
  int xv = v;
  #pragma unroll
  for (int off = 1; off < 64; off <<= 1) {
    int y = __shfl_up(xv, off, 64);
    if (lane >= off) xv += y;
  }
  if (lane == 63) wp[wid] = xv;
  __syncthreads();
  if (tid == 0) { int s = 0; for (int k = 0; k < 4; k++) { int t = wp[k]; wp[k] = s; s += t; } }
  __syncthreads();
  if (tid < nb) bsum[tid] = wp[wid] + xv - v;   // exclusive
}

__global__ void rpfill_kernel(const int* __restrict__ cnt, const int* __restrict__ bsum,
                              int* __restrict__ rp, float* __restrict__ dinv, int n, int E) {
  __shared__ int wp[4];
  int tid = threadIdx.x, lane = tid & 63, wid = tid >> 6;
  int i = blockIdx.x * 256 + tid;
  int v = (i < n) ? cnt[i] : 0;
  int xv = v;
  #pragma unroll
  for (int off = 1; off < 64; off <<= 1) {
    int y = __shfl_up(xv, off, 64);
    if (lane >= off) xv += y;
  }
  if (lane == 63) wp[wid] = xv;
  __syncthreads();
  if (tid == 0) { int s = 0; for (int k = 0; k < 4; k++) { int t = wp[k]; wp[k] = s; s += t; } }
  __syncthreads();
  if (i < n) {
    rp[i] = bsum[blockIdx.x] + wp[wid] + xv - v;
    dinv[i] = rsqrtf((float)(v + 1));
  }
  if (blockIdx.x == 0 && tid == 0) rp[n] = E;
}

__global__ void fill_kernel(const int* __restrict__ src, const int* __restrict__ dst,
                            const int* __restrict__ rp, int* __restrict__ fil,
                            int* __restrict__ csr, int E) {
  int e = blockIdx.x * 256 + threadIdx.x;
  if (e < E) {
    int d = dst[e];
    int pos = rp[d] + atomicAdd(&fil[d], 1);
    csr[pos] = src[e];
  }
}

// ---------------- GCN aggregate (wave/node, chunked edge preload, bf16 h) --
__global__ void gcn_agg_kernel(const __bf16* __restrict__ h, const int* __restrict__ rp,
                               const int* __restrict__ csr, const float* __restrict__ dinv,
                               const float* __restrict__ bias, __bf16* __restrict__ out, int n)
{
  const int lane = threadIdx.x & 63;
  const int v = blockIdx.x * 4 + (threadIdx.x >> 6);
  if (v >= n) return;
  const float dv = dinv[v];
  const int e0 = rp[v], e1 = rp[v + 1];
  float acc[5];
  #pragma unroll
  for (int j = 0; j < 5; j++) acc[j] = dv * (float)h[(size_t)v * FDIM + lane + 64 * j];
  for (int base = e0; base < e1; base += 64) {
    int nn = min(64, e1 - base);
    int s_l = (lane < nn) ? csr[base + lane] : 0;
    float d_l = (lane < nn) ? dinv[s_l] : 0.f;
    for (int j2 = 0; j2 < nn; j2++) {
      int sj = __shfl(s_l, j2, 64);
      float cj = __shfl(d_l, j2, 64);
      const __bf16* hs = h + (size_t)sj * FDIM;
      #pragma unroll
      for (int j = 0; j < 5; j++) acc[j] += cj * (float)hs[lane + 64 * j];
    }
  }
  #pragma unroll
  for (int j = 0; j < 5; j++) {
    float rr = dv * acc[j] + bias[lane + 64 * j];
    out[(size_t)v * FDIM + lane + 64 * j] = (__bf16)fmaxf(rr, 0.f);
  }
}

__device__ __forceinline__ float lrelu(float x) { return x > 0.f ? x : 0.2f * x; }

// ---- merged segment max + denom + alpha (thread per (v,t); as_ L2-resident)
__global__ void mdenom2_kernel(const int* __restrict__ rp, const int* __restrict__ csr,
                               const float* __restrict__ as_, const float* __restrict__ ad_,
                               float* __restrict__ aint, float* __restrict__ aself, int n)
{
  int tid = blockIdx.x * 256 + threadIdx.x;
  if (tid >= n * NHEADS) return;
  int v = tid / NHEADS, t = tid - v * NHEADS;
  int e0 = rp[v], e1 = rp[v + 1];
  float adv = ad_[tid];
  float esf = lrelu(as_[tid] + adv);
  float m = esf;
  for (int e = e0; e < e1; e++) {
    int s = csr[e];
    m = fmaxf(m, lrelu(as_[s * NHEADS + t] + adv));
  }
  float pself = __expf(esf - m);
  float den = pself;
  for (int e = e0; e < e1; e++) {
    int s = csr[e];
    den += __expf(lrelu(as_[s * NHEADS + t] + adv) - m);
  }
  float inv = 1.f / den;
  for (int e = e0; e < e1; e++) {
    int s = csr[e];
    aint[(size_t)e * NHEADS + t] = __expf(lrelu(as_[s * NHEADS + t] + adv) - m) * inv;
  }
  aself[tid] = pself * inv;
}

// ---------------- GAT aggregate (wave/node, interleaved alpha, bf16 h) -----
__global__ void gat_agg_kernel(const __bf16* __restrict__ h, const int* __restrict__ rp,
                               const int* __restrict__ csr, const float* __restrict__ aint,
                               const float* __restrict__ aself, const float* __restrict__ bias,
                               __bf16* __restrict__ out, int n)
{
  const int lane = threadIdx.x & 63;
  const int v = blockIdx.x * 4 + (threadIdx.x >> 6);
  if (v >= n) return;
  const int hb = lane >> 5;   // head of channel lane+64j is 2j+hb
  const int e0 = rp[v], e1 = rp[v + 1];
  const float* asf = aself + (size_t)v * NHEADS;
  float acc[5];
  #pragma unroll
  for (int j = 0; j < 5; j++)
    acc[j] = asf[2 * j + hb] * (float)h[(size_t)v * FDIM + lane + 64 * j];
  for (int base = e0; base < e1; base += 64) {
    int nn = min(64, e1 - base);
    int s_l = (lane < nn) ? csr[base + lane] : 0;
    for (int j2 = 0; j2 < nn; j2++) {
      int sj = __shfl(s_l, j2, 64);
      const float* al = aint + (size_t)(base + j2) * NHEADS;
      const __bf16* hs = h + (size_t)sj * FDIM;
      #pragma unroll
      for (int j = 0; j < 5; j++)
        acc[j] += al[2 * j + hb] * (float)hs[lane + 64 * j];
    }
  }
  #pragma unroll
  for (int j = 0; j < 5; j++) {
    int c = lane + 64 * j;
    float rr = acc[j] + bias[c];
    out[(size_t)v * FDIM + c] = (__bf16)fmaxf(rr, 0.f);
  }
}

// ---------------- batch boundaries + pooling ----------------
__global__ void bstart_kernel(const int* __restrict__ batch, int* __restrict__ bstart,
                              int n, int B_) {
  int v = blockIdx.x * 256 + threadIdx.x;
  if (v > n) return;
  int bv = (v < n) ? batch[v] : B_;
  int bp = (v == 0) ? -1 : batch[v - 1];
  for (int gg = bp + 1; gg <= bv; gg++) bstart[gg] = v;
}

__global__ void pool_kernel(const __bf16* __restrict__ xin, const int* __restrict__ bstart,
                            float* __restrict__ g) {
  int gid = blockIdx.x;
  int c = blockIdx.y * 64 + threadIdx.x;
  int s = bstart[gid], e = bstart[gid + 1];
  float mx = -__builtin_inff(), sm = 0.f;
  for (int v = s; v < e; v++) {
    float val = (float)xin[(size_t)v * FDIM + c];
    mx = fmaxf(mx, val);
    sm += val;
  }
  float cntf = (float)(e - s);
  g[gid * (2 * FDIM) + c] = mx;
  g[gid * (2 * FDIM) + FDIM + c] = sm / fmaxf(cntf, 1.f);
}

// ---------------- launch ----------------
extern "C" void kernel_launch(void* const* d_in, const int* in_sizes, int n_in,
                              void* d_out, int out_size, void* d_ws, size_t ws_size,
                              hipStream_t stream)
{
  const int N = in_sizes[0] / FDIM;
  const int E = in_sizes[2] / 2;
  const int NB = (N + 255) / 256;

  const float* x[2]   = {(const float*)d_in[0], (const float*)d_in[1]};
  const int*   ei[2]  = {(const int*)d_in[2], (const int*)d_in[3]};
  const int*   bat[2] = {(const int*)d_in[4], (const int*)d_in[5]};
  const float* W_gcn   = (const float*)d_in[6];
  const float* b_gcn   = (const float*)d_in[7];
  const float* W_gat   = (const float*)d_in[8];
  const float* att_src = (const float*)d_in[9];
  const float* att_dst = (const float*)d_in[10];
  const float* b_gat   = (const float*)d_in[11];
  const float* W_fc_g1 = (const float*)d_in[12];
  const float* b_fc_g1 = (const float*)d_in[13];
  const float* W_fc_g2 = (const float*)d_in[14];
  const float* b_fc_g2 = (const float*)d_in[15];
  const float* W_fc1   = (const float*)d_in[16];
  const float* b_fc1   = (const float*)d_in[17];
  const float* W_fc2   = (const float*)d_in[18];
  const float* b_fc2   = (const float*)d_in[19];
  const float* W_out   = (const float*)d_in[20];
  const float* b_out   = (const float*)d_in[21];
  float* outp = (float*)d_out;

  char* ws = (char*)d_ws;
  size_t off = 0;
  auto alloc = [&](size_t bytes) -> char* {
    char* p = ws + off;
    off += (bytes + 255) & ~(size_t)255;
    return p;
  };
  int*    cnt    = (int*)alloc((size_t)N * 4);
  int*    fil    = (int*)alloc((size_t)N * 4);
  size_t  zero_span = (size_t)((char*)fil - (char*)cnt) + ((size_t)N * 4 + 255 & ~(size_t)255);
  int*    rp     = (int*)alloc((size_t)(N + 1) * 4);
  int*    bsum   = (int*)alloc((size_t)NB * 4);
  int*    csr    = (int*)alloc((size_t)E * 4);
  float*  dinv   = (float*)alloc((size_t)N * 4);
  int*    bstart = (int*)alloc((size_t)(NGR + 1) * 4);
  __bf16* WgcnT  = (__bf16*)alloc((size_t)FDIM * FDIM * 2);
  __bf16* WgatT  = (__bf16*)alloc((size_t)FDIM * FDIM * 2);
  __bf16* hbuf   = (__bf16*)alloc((size_t)N * FDIM * 2);
  __bf16* xbuf   = (__bf16*)alloc((size_t)N * FDIM * 2);
  float*  as_    = (float*)alloc((size_t)N * NHEADS * 4);
  float*  ad_    = (float*)alloc((size_t)N * NHEADS * 4);
  float*  aint   = (float*)alloc((size_t)E * NHEADS * 4);
  float*  aself  = (float*)alloc((size_t)N * NHEADS * 4);
  float*  g      = (float*)alloc((size_t)2 * NGR * 2 * FDIM * 4);   // both branches
  float*  t1     = (float*)alloc((size_t)2 * NGR * 1500 * 4);       // both branches
  float*  xc     = (float*)alloc((size_t)NGR * 256 * 4);
  float*  t2     = (float*)alloc((size_t)NGR * 1024 * 4);
  float*  t3     = (float*)alloc((size_t)NGR * 512 * 4);
  float*  part   = (float*)alloc((size_t)8 * 512 * 512 * 4);        // split-K partials (8 MB)
  if (off > ws_size) return;  // workspace too small: bail (visible as absmax fail)

  wconv_kernel<<<(FDIM * FDIM) / 256, 256, 0, stream>>>(W_gcn, WgcnT);
  wconv_kernel<<<(FDIM * FDIM) / 256, 256, 0, stream>>>(W_gat, WgatT);

  for (int br = 0; br < 2; br++) {
    hipMemsetAsync(cnt, 0, zero_span, stream);
    const int* srcp = ei[br];
    const int* dstp = ei[br] + E;
    count_kernel<<<(E + 255) / 256, 256, 0, stream>>>(dstp, cnt, E);
    bsum_kernel<<<NB, 256, 0, stream>>>(cnt, bsum, N);
    bscan_kernel<<<1, 256, 0, stream>>>(bsum, NB);
    rpfill_kernel<<<NB, 256, 0, stream>>>(cnt, bsum, rp, dinv, N, E);
    fill_kernel<<<(E + 255) / 256, 256, 0, stream>>>(srcp, dstp, rp, fil, csr, E);

    int g320 = (N + 63) / 64;
    gemm320v3_kernel<float, false><<<g320, 256, 0, stream>>>(
        x[br], WgcnT, hbuf, N, nullptr, nullptr, nullptr, nullptr);
    gcn_agg_kernel<<<(N + 3) / 4, 256, 0, stream>>>(hbuf, rp, csr, dinv, b_gcn, xbuf, N);
    gemm320v3_kernel<__bf16, true><<<g320, 256, 0, stream>>>(
        xbuf, WgatT, hbuf, N, att_src, att_dst, as_, ad_);

    mdenom2_kernel<<<(N * NHEADS + 255) / 256, 256, 0, stream>>>(rp, csr, as_, ad_, aint, aself, N);
    gat_agg_kernel<<<(N + 3) / 4, 256, 0, stream>>>(hbuf, rp, csr, aint, aself, b_gat, xbuf, N);

    bstart_kernel<<<(N + 256) / 256, 256, 0, stream>>>(bat[br], bstart, N, NGR);
    dim3 gpool(NGR, FDIM / 64);
    pool_kernel<<<gpool, 64, 0, stream>>>(xbuf, bstart, g + (size_t)br * NGR * 2 * FDIM);
  }

  // ---- batched FC head: M=512 covers both branches ----
  {
    dim3 gfc1((512 + BM - 1) / BM, (1500 + BN - 1) / BN);
    gemm_bf16_kernel<3><<<gfc1, 256, 0, stream>>>(g, W_fc_g1, t1, b_fc_g1, 512, 1500, 2 * FDIM, 1500);
    int S = 8, KS = ((1500 + S * BK - 1) / (S * BK)) * BK;
    dim3 gfc2((512 + BM - 1) / BM, (128 + BN - 1) / BN, S);
    gemm_splitk_kernel<<<gfc2, 256, 0, stream>>>(t1, W_fc_g2, part, 512, 128, 1500, KS);
    reduce_kernel<2, true><<<(512 * 128 + 255) / 256, 256, 0, stream>>>(part, xc, b_fc_g2, 512, 128, S, 256);
  }
  {
    dim3 gx1((NGR + BM - 1) / BM, (1024 + BN - 1) / BN);
    gemm_bf16_kernel<3><<<gx1, 256, 0, stream>>>(xc, W_fc1, t2, b_fc1, NGR, 1024, 256, 1024);
    int S = 4, KS = ((1024 + S * BK - 1) / (S * BK)) * BK;
    dim3 gx2((NGR + BM - 1) / BM, (512 + BN - 1) / BN, S);
    gemm_splitk_kernel<<<gx2, 256, 0, stream>>>(t2, W_fc2, part, NGR, 512, 1024, KS);
    reduce_kernel<3, false><<<(NGR * 512 + 255) / 256, 256, 0, stream>>>(part, t3, b_fc2, NGR, 512, S, 512);
    int S2 = 4, KS2 = ((512 + S2 * BK - 1) / (S2 * BK)) * BK;
    dim3 gx3((NGR + BM - 1) / BM, 1, S2);
    gemm_splitk_kernel<<<gx3, 256, 0, stream>>>(t3, W_out, part, NGR, 2, 512, KS2);
    reduce_kernel<2, false><<<(NGR * 2 + 255) / 256, 256, 0, stream>>>(part, outp, b_out, NGR, 2, S2, 2);
  }
}

// Round 9
// 745.870 us; speedup vs baseline: 1.2098x; 1.0112x over previous
//
#include <hip/hip_runtime.h>
#include <type_traits>

#define FDIM 320
#define NHEADS 10
#define NGR 256

typedef __bf16 bf16x8 __attribute__((ext_vector_type(8)));
typedef float f32x4 __attribute__((ext_vector_type(4)));

// ---------------- weight transpose+convert (both weights, one launch) ------
__global__ void wconv2_kernel(const float* __restrict__ Wg, const float* __restrict__ Wa,
                              __bf16* __restrict__ Tg, __bf16* __restrict__ Ta) {
  int idx = blockIdx.x * 256 + threadIdx.x;          // grid 800*256 = 2*102400
  bool first = idx < FDIM * FDIM;
  const float* W = first ? Wg : Wa;
  __bf16* T = first ? Tg : Ta;
  int i2 = first ? idx : idx - FDIM * FDIM;
  int k = i2 / FDIM, c = i2 - k * FDIM;
  T[c * FDIM + k] = (__bf16)W[i2];
}

// ---------------- node GEMM v3: full-N, BK=32, LDS dbuf, async reg-stage ---
#define GLSTR 40

template<typename TA, bool SCORES>
__global__ __launch_bounds__(256, 2) void gemm320v3_kernel(
    const TA* __restrict__ A, const __bf16* __restrict__ Wt,
    __bf16* __restrict__ C, int M,
    const float* __restrict__ att_s, const float* __restrict__ att_d,
    float* __restrict__ as_, float* __restrict__ ad_)
{
  __shared__ __bf16 As[2][64 * GLSTR];
  __shared__ __bf16 Bs[2][320 * GLSTR];

  const int tid = threadIdx.x;
  const int lane = tid & 63;
  const int w = tid >> 6;
  const int wr = w >> 1, wc = w & 1;
  const int r = lane & 15, kg = lane >> 4;
  const int m0 = blockIdx.x * 64;

  const int brow = tid >> 2, bq = tid & 3;
  const int gmrow = m0 + brow;
  const bool arow_ok = gmrow < M;

  bf16x8 bstg[5];
  bf16x8 astg;
  float4 af32a, af32b;

  auto stage_load = [&](int k0) {
    #pragma unroll
    for (int i = 0; i < 5; i++) {
      int ch = tid + i * 256;
      int col = ch >> 2, kc = ch & 3;
      bstg[i] = *(const bf16x8*)(Wt + (size_t)col * FDIM + k0 + kc * 8);
    }
    if constexpr (std::is_same_v<TA, float>) {
      if (arow_ok) {
        const float4* ap = (const float4*)(A + (size_t)gmrow * FDIM + k0 + bq * 8);
        af32a = ap[0]; af32b = ap[1];
      }
    } else {
      if (arow_ok) astg = *(const bf16x8*)(A + (size_t)gmrow * FDIM + k0 + bq * 8);
    }
  };
  auto stage_write = [&](int b) {
    #pragma unroll
    for (int i = 0; i < 5; i++) {
      int ch = tid + i * 256;
      int col = ch >> 2, kc = ch & 3;
      *(bf16x8*)&Bs[b][col * GLSTR + kc * 8] = bstg[i];
    }
    bf16x8 v = {};
    if constexpr (std::is_same_v<TA, float>) {
      if (arow_ok) {
        v[0]=(__bf16)af32a.x; v[1]=(__bf16)af32a.y; v[2]=(__bf16)af32a.z; v[3]=(__bf16)af32a.w;
        v[4]=(__bf16)af32b.x; v[5]=(__bf16)af32b.y; v[6]=(__bf16)af32b.z; v[7]=(__bf16)af32b.w;
      }
    } else {
      if (arow_ok) v = astg;
    }
    *(bf16x8*)&As[b][brow * GLSTR + bq * 8] = v;
  };

  f32x4 acc0[10], acc1[10];
  #pragma unroll
  for (int i = 0; i < 10; i++) { acc0[i] = (f32x4){0,0,0,0}; acc1[i] = (f32x4){0,0,0,0}; }

  stage_load(0);
  stage_write(0);
  __syncthreads();

  int cur = 0;
  for (int k = 0; k < 10; k++) {
    if (k < 9) stage_load((k + 1) * 32);
    {
      bf16x8 a0 = *(const bf16x8*)&As[cur][(wr*32 + r)      * GLSTR + kg*8];
      bf16x8 a1 = *(const bf16x8*)&As[cur][(wr*32 + 16 + r) * GLSTR + kg*8];
      #pragma unroll
      for (int nf = 0; nf < 10; nf++) {
        bf16x8 b = *(const bf16x8*)&Bs[cur][(wc*160 + nf*16 + r) * GLSTR + kg*8];
        acc0[nf] = __builtin_amdgcn_mfma_f32_16x16x32_bf16(a0, b, acc0[nf], 0, 0, 0);
        acc1[nf] = __builtin_amdgcn_mfma_f32_16x16x32_bf16(a1, b, acc1[nf], 0, 0, 0);
      }
    }
    if (k < 9) {
      stage_write(cur ^ 1);
      __syncthreads();
      cur ^= 1;
    }
  }

  // ---- store C ----
  #pragma unroll
  for (int nf = 0; nf < 10; nf++) {
    int gn = wc*160 + nf*16 + r;
    #pragma unroll
    for (int q = 0; q < 4; q++) {
      int gm0 = m0 + wr*32 + kg*4 + q;
      if (gm0 < M)       C[(size_t)gm0 * FDIM + gn] = (__bf16)acc0[nf][q];
      int gm1 = gm0 + 16;
      if (gm1 < M)       C[(size_t)gm1 * FDIM + gn] = (__bf16)acc1[nf][q];
    }
  }

  // ---- fused GAT scores ----
  if constexpr (SCORES) {
    #pragma unroll
    for (int th = 0; th < 5; th++) {
      int t = wc * 5 + th;
      float s0 = att_s[t*32 + r],      s1 = att_s[t*32 + 16 + r];
      float d0 = att_d[t*32 + r],      d1 = att_d[t*32 + 16 + r];
      #pragma unroll
      for (int q = 0; q < 4; q++) {
        float ps0 = acc0[2*th][q]*s0 + acc0[2*th+1][q]*s1;
        float ps1 = acc1[2*th][q]*s0 + acc1[2*th+1][q]*s1;
        float pd0 = acc0[2*th][q]*d0 + acc0[2*th+1][q]*d1;
        float pd1 = acc1[2*th][q]*d0 + acc1[2*th+1][q]*d1;
        #pragma unroll
        for (int off = 1; off < 16; off <<= 1) {
          ps0 += __shfl_xor(ps0, off, 16);
          ps1 += __shfl_xor(ps1, off, 16);
          pd0 += __shfl_xor(pd0, off, 16);
          pd1 += __shfl_xor(pd1, off, 16);
        }
        if (r == 0) {
          int row0 = m0 + wr*32 + kg*4 + q;
          if (row0 < M) { as_[row0*NHEADS + t] = ps0; ad_[row0*NHEADS + t] = pd0; }
          int row1 = row0 + 16;
          if (row1 < M) { as_[row1*NHEADS + t] = ps1; ad_[row1*NHEADS + t] = pd1; }
        }
      }
    }
  }
}

// ---------------- generic GEMM (FC layers): C = A*B, f32 in/out ------------
#define BM 128
#define BN 64
#define BK 32
#define LSTR 56

template<int FLAGS>  // bit0: relu, bit1: bias
__global__ __launch_bounds__(256) void gemm_bf16_kernel(
    const float* __restrict__ A, const float* __restrict__ B,
    float* __restrict__ C, const float* __restrict__ bias,
    int M, int N, int K, int ldc)
{
  __shared__ __bf16 As[BM * LSTR];
  __shared__ __bf16 Bs[BN * LSTR];

  const int tid = threadIdx.x;
  const int lane = tid & 63;
  const int w = tid >> 6;
  const int wm = w >> 1, wn = w & 1;
  const int r = lane & 15, kg = lane >> 4;
  const int m0 = blockIdx.x * BM, n0 = blockIdx.y * BN;

  f32x4 acc[4][2];
  #pragma unroll
  for (int i = 0; i < 4; i++)
    #pragma unroll
    for (int j = 0; j < 2; j++)
      acc[i][j] = (f32x4){0.f, 0.f, 0.f, 0.f};

  const int arow = tid >> 1, ahalf = tid & 1;
  const int bk = tid >> 3, bn = (tid & 7) * 8;

  for (int k0 = 0; k0 < K; k0 += BK) {
    __syncthreads();
    {
      int gm = m0 + arow;
      int kbase = k0 + ahalf * 16;
      float tmp[16];
      if (gm < M && kbase + 16 <= K) {
        const float4* ap = (const float4*)(A + (size_t)gm * K + kbase);
        #pragma unroll
        for (int q = 0; q < 4; q++) {
          float4 v = ap[q];
          tmp[q*4+0] = v.x; tmp[q*4+1] = v.y; tmp[q*4+2] = v.z; tmp[q*4+3] = v.w;
        }
      } else {
        #pragma unroll
        for (int q = 0; q < 16; q++) {
          int kk = kbase + q;
          tmp[q] = (gm < M && kk < K) ? A[(size_t)gm * K + kk] : 0.f;
        }
      }
      bf16x8 v0, v1;
      #pragma unroll
      for (int q = 0; q < 8; q++) { v0[q] = (__bf16)tmp[q]; v1[q] = (__bf16)tmp[q+8]; }
      bf16x8* dp = (bf16x8*)&As[arow * LSTR + ahalf * 16];
      dp[0] = v0; dp[1] = v1;
    }
    {
      int gk = k0 + bk;
      float tb[8];
      if (gk < K && n0 + bn + 8 <= N) {
        const float4* bp = (const float4*)(B + (size_t)gk * N + n0 + bn);
        float4 u0 = bp[0], u1 = bp[1];
        tb[0]=u0.x; tb[1]=u0.y; tb[2]=u0.z; tb[3]=u0.w;
        tb[4]=u1.x; tb[5]=u1.y; tb[6]=u1.z; tb[7]=u1.w;
      } else {
        #pragma unroll
        for (int q = 0; q < 8; q++) {
          int gn = n0 + bn + q;
          tb[q] = (gk < K && gn < N) ? B[(size_t)gk * N + gn] : 0.f;
        }
      }
      #pragma unroll
      for (int q = 0; q < 8; q++) Bs[(bn + q) * LSTR + bk] = (__bf16)tb[q];
    }
    __syncthreads();
    bf16x8 af[4], bfr[2];
    #pragma unroll
    for (int mf = 0; mf < 4; mf++)
      af[mf] = *(const bf16x8*)&As[(wm*64 + mf*16 + r) * LSTR + kg*8];
    #pragma unroll
    for (int nf = 0; nf < 2; nf++)
      bfr[nf] = *(const bf16x8*)&Bs[(wn*32 + nf*16 + r) * LSTR + kg*8];
    #pragma unroll
    for (int mf = 0; mf < 4; mf++)
      #pragma unroll
      for (int nf = 0; nf < 2; nf++)
        acc[mf][nf] = __builtin_amdgcn_mfma_f32_16x16x32_bf16(af[mf], bfr[nf], acc[mf][nf], 0, 0, 0);
  }

  #pragma unroll
  for (int mf = 0; mf < 4; mf++) {
    #pragma unroll
    for (int nf = 0; nf < 2; nf++) {
      #pragma unroll
      for (int q = 0; q < 4; q++) {
        int gm = m0 + wm*64 + mf*16 + kg*4 + q;
        int gn = n0 + wn*32 + nf*16 + r;
        if (gm < M && gn < N) {
          float v = acc[mf][nf][q];
          if (FLAGS & 2) v += bias[gn];
          if (FLAGS & 1) v = fmaxf(v, 0.f);
          C[(size_t)gm * ldc + gn] = v;
        }
      }
    }
  }
}

// ---------------- split-K GEMM: P[s][M][N] partials ----------------
__global__ __launch_bounds__(256) void gemm_splitk_kernel(
    const float* __restrict__ A, const float* __restrict__ B,
    float* __restrict__ P, int M, int N, int K, int KS)
{
  __shared__ __bf16 As[BM * LSTR];
  __shared__ __bf16 Bs[BN * LSTR];

  const int tid = threadIdx.x;
  const int lane = tid & 63;
  const int w = tid >> 6;
  const int wm = w >> 1, wn = w & 1;
  const int r = lane & 15, kg = lane >> 4;
  const int m0 = blockIdx.x * BM, n0 = blockIdx.y * BN;
  const int kstart = blockIdx.z * KS;
  const int kend = min(K, kstart + KS);

  f32x4 acc[4][2];
  #pragma unroll
  for (int i = 0; i < 4; i++)
    #pragma unroll
    for (int j = 0; j < 2; j++)
      acc[i][j] = (f32x4){0.f, 0.f, 0.f, 0.f};

  const int arow = tid >> 1, ahalf = tid & 1;
  const int bk = tid >> 3, bn = (tid & 7) * 8;

  for (int k0 = kstart; k0 < kend; k0 += BK) {
    __syncthreads();
    {
      int gm = m0 + arow;
      int kbase = k0 + ahalf * 16;
      float tmp[16];
      if (gm < M && kbase + 16 <= kend) {
        const float4* ap = (const float4*)(A + (size_t)gm * K + kbase);
        #pragma unroll
        for (int q = 0; q < 4; q++) {
          float4 v = ap[q];
          tmp[q*4+0] = v.x; tmp[q*4+1] = v.y; tmp[q*4+2] = v.z; tmp[q*4+3] = v.w;
        }
      } else {
        #pragma unroll
        for (int q = 0; q < 16; q++) {
          int kk = kbase + q;
          tmp[q] = (gm < M && kk < kend) ? A[(size_t)gm * K + kk] : 0.f;
        }
      }
      bf16x8 v0, v1;
      #pragma unroll
      for (int q = 0; q < 8; q++) { v0[q] = (__bf16)tmp[q]; v1[q] = (__bf16)tmp[q+8]; }
      bf16x8* dp = (bf16x8*)&As[arow * LSTR + ahalf * 16];
      dp[0] = v0; dp[1] = v1;
    }
    {
      int gk = k0 + bk;
      float tb[8];
      if (gk < kend && n0 + bn + 8 <= N) {
        const float4* bp = (const float4*)(B + (size_t)gk * N + n0 + bn);
        float4 u0 = bp[0], u1 = bp[1];
        tb[0]=u0.x; tb[1]=u0.y; tb[2]=u0.z; tb[3]=u0.w;
        tb[4]=u1.x; tb[5]=u1.y; tb[6]=u1.z; tb[7]=u1.w;
      } else {
        #pragma unroll
        for (int q = 0; q < 8; q++) {
          int gn = n0 + bn + q;
          tb[q] = (gk < kend && gn < N) ? B[(size_t)gk * N + gn] : 0.f;
        }
      }
      #pragma unroll
      for (int q = 0; q < 8; q++) Bs[(bn + q) * LSTR + bk] = (__bf16)tb[q];
    }
    __syncthreads();
    bf16x8 af[4], bfr[2];
    #pragma unroll
    for (int mf = 0; mf < 4; mf++)
      af[mf] = *(const bf16x8*)&As[(wm*64 + mf*16 + r) * LSTR + kg*8];
    #pragma unroll
    for (int nf = 0; nf < 2; nf++)
      bfr[nf] = *(const bf16x8*)&Bs[(wn*32 + nf*16 + r) * LSTR + kg*8];
    #pragma unroll
    for (int mf = 0; mf < 4; mf++)
      #pragma unroll
      for (int nf = 0; nf < 2; nf++)
        acc[mf][nf] = __builtin_amdgcn_mfma_f32_16x16x32_bf16(af[mf], bfr[nf], acc[mf][nf], 0, 0, 0);
  }

  float* Pp = P + (size_t)blockIdx.z * M * N;
  #pragma unroll
  for (int mf = 0; mf < 4; mf++) {
    #pragma unroll
    for (int nf = 0; nf < 2; nf++) {
      #pragma unroll
      for (int q = 0; q < 4; q++) {
        int gm = m0 + wm*64 + mf*16 + kg*4 + q;
        int gn = n0 + wn*32 + nf*16 + r;
        if (gm < M && gn < N)
          Pp[(size_t)gm * N + gn] = acc[mf][nf][q];
      }
    }
  }
}

// reduce partials; STACK: rows M/2.. go to cols N.. (fc_g2 branch packing)
template<int FLAGS, bool STACK>
__global__ void reduce_kernel(const float* __restrict__ P, float* __restrict__ C,
                              const float* __restrict__ bias, int M, int N, int S, int ldc)
{
  int i = blockIdx.x * 256 + threadIdx.x;
  if (i >= M * N) return;
  float v = 0.f;
  for (int s = 0; s < S; s++) v += P[(size_t)s * M * N + i];
  int row = i / N, col = i - row * N;
  if (FLAGS & 2) v += bias[col];
  if (FLAGS & 1) v = fmaxf(v, 0.f);
  if (STACK) { if (row >= (M >> 1)) { row -= (M >> 1); col += N; } }
  C[(size_t)row * ldc + col] = v;
}

// ---------------- CSR build ----------------
__global__ void count_kernel(const int* __restrict__ dst, int* __restrict__ cnt, int E) {
  int e = blockIdx.x * 256 + threadIdx.x;
  if (e < E) atomicAdd(&cnt[dst[e]], 1);
}

__global__ void bsum_kernel(const int* __restrict__ cnt, int* __restrict__ bsum, int n) {
  __shared__ int wp[4];
  int tid = threadIdx.x, lane = tid & 63, wid = tid >> 6;
  int i = blockIdx.x * 256 + tid;
  int v = (i < n) ? cnt[i] : 0;
  #pragma unroll
  for (int off = 32; off >= 1; off >>= 1) v += __shfl_xor(v, off, 64);
  if (lane == 0) wp[wid] = v;
  __syncthreads();
  if (tid == 0) bsum[blockIdx.x] = wp[0] + wp[1] + wp[2] + wp[3];
}

__global__ void bscan_kernel(int* __restrict__ bsum, int nb) {
  __shared__ int wp[4];
  int tid = threadIdx.x, lane = tid & 63, wid = tid >> 6;
  int v = (tid < nb) ? bsum[tid] : 0;
  int xv = v;
  #pragma unroll
  for (int off = 1; off < 64; off <<= 1) {
    int y = __shfl_up(xv, off, 64);
    if (lane >= off) xv += y;
  }
  if (lane == 63) wp[wid] = xv;
  __syncthreads();
  if (tid == 0) { int s = 0; for (int k = 0; k < 4; k++) { int t = wp[k]; wp[k] = s; s += t; } }
  __syncthreads();
  if (tid < nb) bsum[tid] = wp[wid] + xv - v;   // exclusive
}

__global__ void rpfill_kernel(const int* __restrict__ cnt, const int* __restrict__ bsum,
                              int* __restrict__ rp, float* __restrict__ dinv, int n, int E) {
  __shared__ int wp[4];
  int tid = threadIdx.x, lane = tid & 63, wid = tid >> 6;
  int i = blockIdx.x * 256 + tid;
  int v = (i < n) ? cnt[i] : 0;
  int xv = v;
  #pragma unroll
  for (int off = 1; off < 64; off <<= 1) {
    int y = __shfl_up(xv, off, 64);
    if (lane >= off) xv += y;
  }
  if (lane == 63) wp[wid] = xv;
  __syncthreads();
  if (tid == 0) { int s = 0; for (int k = 0; k < 4; k++) { int t = wp[k]; wp[k] = s; s += t; } }
  __syncthreads();
  if (i < n) {
    rp[i] = bsum[blockIdx.x] + wp[wid] + xv - v;
    dinv[i] = rsqrtf((float)(v + 1));
  }
  if (blockIdx.x == 0 && tid == 0) rp[n] = E;
}

__global__ void fill_kernel(const int* __restrict__ src, const int* __restrict__ dst,
                            const int* __restrict__ rp, int* __restrict__ fil,
                            int* __restrict__ csr, int E) {
  int e = blockIdx.x * 256 + threadIdx.x;
  if (e < E) {
    int d = dst[e];
    int pos = rp[d] + atomicAdd(&fil[d], 1);
    csr[pos] = src[e];
  }
}

// ---------------- GCN aggregate (wave/node, 40-lane bf16x8 loads) ----------
__global__ void gcn_agg_kernel(const __bf16* __restrict__ h, const int* __restrict__ rp,
                               const int* __restrict__ csr, const float* __restrict__ dinv,
                               const float* __restrict__ bias, __bf16* __restrict__ out, int n)
{
  const int lane = threadIdx.x & 63;
  const int v = blockIdx.x * 4 + (threadIdx.x >> 6);
  if (v >= n) return;
  const bool act = lane < 40;
  const float dv = dinv[v];
  const int e0 = rp[v], e1 = rp[v + 1];
  float acc[8], bia[8];
  if (act) {
    bf16x8 hv = *(const bf16x8*)(h + (size_t)v * FDIM + 8 * lane);
    const float4* bp = (const float4*)(bias + 8 * lane);
    float4 b0 = bp[0], b1 = bp[1];
    bia[0]=b0.x; bia[1]=b0.y; bia[2]=b0.z; bia[3]=b0.w;
    bia[4]=b1.x; bia[5]=b1.y; bia[6]=b1.z; bia[7]=b1.w;
    #pragma unroll
    for (int j = 0; j < 8; j++) acc[j] = dv * (float)hv[j];
  }
  for (int base = e0; base < e1; base += 64) {
    int nn = min(64, e1 - base);
    int s_l = (lane < nn) ? csr[base + lane] : 0;
    float d_l = (lane < nn) ? dinv[s_l] : 0.f;
    for (int j2 = 0; j2 < nn; j2++) {
      int sj = __shfl(s_l, j2, 64);
      float cj = __shfl(d_l, j2, 64);
      if (act) {
        bf16x8 hv = *(const bf16x8*)(h + (size_t)sj * FDIM + 8 * lane);
        #pragma unroll
        for (int j = 0; j < 8; j++) acc[j] += cj * (float)hv[j];
      }
    }
  }
  if (act) {
    bf16x8 o;
    #pragma unroll
    for (int j = 0; j < 8; j++) o[j] = (__bf16)fmaxf(dv * acc[j] + bia[j], 0.f);
    *(bf16x8*)(out + (size_t)v * FDIM + 8 * lane) = o;
  }
}

__device__ __forceinline__ float lrelu(float x) { return x > 0.f ? x : 0.2f * x; }

// ---- online segment softmax stats: one pass; writes m, 1/den, aself -------
__global__ void mdenom3_kernel(const int* __restrict__ rp, const int* __restrict__ csr,
                               const float* __restrict__ as_, const float* __restrict__ ad_,
                               float* __restrict__ minv, float* __restrict__ invden,
                               float* __restrict__ aself, int n)
{
  int tid = blockIdx.x * 256 + threadIdx.x;
  if (tid >= n * NHEADS) return;
  int v = tid / NHEADS, t = tid - v * NHEADS;
  int e0 = rp[v], e1 = rp[v + 1];
  float adv = ad_[tid];
  float esf = lrelu(as_[tid] + adv);
  float m = esf, den = 1.f;
  for (int e = e0; e < e1; e++) {
    int s = csr[e];
    float ev = lrelu(as_[s * NHEADS + t] + adv);
    float nm = fmaxf(m, ev);
    den = den * __expf(m - nm) + __expf(ev - nm);
    m = nm;
  }
  float inv = 1.f / den;
  minv[tid] = m;
  invden[tid] = inv;
  aself[tid] = __expf(esf - m) * inv;
}

// ---------------- GAT aggregate (40-lane bf16x8, inline alpha) -------------
__global__ void gat_agg_kernel(const __bf16* __restrict__ h, const int* __restrict__ rp,
                               const int* __restrict__ csr, const float* __restrict__ as_,
                               const float* __restrict__ ad_, const float* __restrict__ minv,
                               const float* __restrict__ invden, const float* __restrict__ aself,
                               const float* __restrict__ bias, __bf16* __restrict__ out, int n)
{
  const int lane = threadIdx.x & 63;
  const int v = blockIdx.x * 4 + (threadIdx.x >> 6);
  if (v >= n) return;
  const bool act = lane < 40;
  const int hl = lane >> 2;     // head of channels 8*lane..8*lane+7
  const int e0 = rp[v], e1 = rp[v + 1];
  float adv_t = 0.f, m_t = 0.f, inv_t = 0.f;
  float acc[8], bia[8];
  if (act) {
    adv_t = ad_[v * NHEADS + hl];
    m_t   = minv[v * NHEADS + hl];
    inv_t = invden[v * NHEADS + hl];
    float aslf = aself[v * NHEADS + hl];
    bf16x8 hv = *(const bf16x8*)(h + (size_t)v * FDIM + 8 * lane);
    const float4* bp = (const float4*)(bias + 8 * lane);
    float4 b0 = bp[0], b1 = bp[1];
    bia[0]=b0.x; bia[1]=b0.y; bia[2]=b0.z; bia[3]=b0.w;
    bia[4]=b1.x; bia[5]=b1.y; bia[6]=b1.z; bia[7]=b1.w;
    #pragma unroll
    for (int j = 0; j < 8; j++) acc[j] = aslf * (float)hv[j];
  }
  for (int base = e0; base < e1; base += 64) {
    int nn = min(64, e1 - base);
    int s_l = (lane < nn) ? csr[base + lane] : 0;
    for (int j2 = 0; j2 < nn; j2++) {
      int sj = __shfl(s_l, j2, 64);
      if (act) {
        float asv = as_[sj * NHEADS + hl];
        float al = __expf(lrelu(asv + adv_t) - m_t) * inv_t;
        bf16x8 hv = *(const bf16x8*)(h + (size_t)sj * FDIM + 8 * lane);
        #pragma unroll
        for (int j = 0; j < 8; j++) acc[j] += al * (float)hv[j];
      }
    }
  }
  if (act) {
    bf16x8 o;
    #pragma unroll
    for (int j = 0; j < 8; j++) o[j] = (__bf16)fmaxf(acc[j] + bia[j], 0.f);
    *(bf16x8*)(out + (size_t)v * FDIM + 8 * lane) = o;
  }
}

// ---------------- batch boundaries + pooling ----------------
__global__ void bstart_kernel(const int* __restrict__ batch, int* __restrict__ bstart,
                              int n, int B_) {
  int v = blockIdx.x * 256 + threadIdx.x;
  if (v > n) return;
  int bv = (v < n) ? batch[v] : B_;
  int bp = (v == 0) ? -1 : batch[v - 1];
  for (int gg = bp + 1; gg <= bv; gg++) bstart[gg] = v;
}

__global__ void pool_kernel(const __bf16* __restrict__ xin, const int* __restrict__ bstart,
                            float* __restrict__ g) {
  int gid = blockIdx.x;
  int c = blockIdx.y * 64 + threadIdx.x;
  int s = bstart[gid], e = bstart[gid + 1];
  float mx = -__builtin_inff(), sm = 0.f;
  for (int v = s; v < e; v++) {
    float val = (float)xin[(size_t)v * FDIM + c];
    mx = fmaxf(mx, val);
    sm += val;
  }
  float cntf = (float)(e - s);
  g[gid * (2 * FDIM) + c] = mx;
  g[gid * (2 * FDIM) + FDIM + c] = sm / fmaxf(cntf, 1.f);
}

// ---------------- launch ----------------
extern "C" void kernel_launch(void* const* d_in, const int* in_sizes, int n_in,
                              void* d_out, int out_size, void* d_ws, size_t ws_size,
                              hipStream_t stream)
{
  const int N = in_sizes[0] / FDIM;
  const int E = in_sizes[2] / 2;
  const int NB = (N + 255) / 256;

  const float* x[2]   = {(const float*)d_in[0], (const float*)d_in[1]};
  const int*   ei[2]  = {(const int*)d_in[2], (const int*)d_in[3]};
  const int*   bat[2] = {(const int*)d_in[4], (const int*)d_in[5]};
  const float* W_gcn   = (const float*)d_in[6];
  const float* b_gcn   = (const float*)d_in[7];
  const float* W_gat   = (const float*)d_in[8];
  const float* att_src = (const float*)d_in[9];
  const float* att_dst = (const float*)d_in[10];
  const float* b_gat   = (const float*)d_in[11];
  const float* W_fc_g1 = (const float*)d_in[12];
  const float* b_fc_g1 = (const float*)d_in[13];
  const float* W_fc_g2 = (const float*)d_in[14];
  const float* b_fc_g2 = (const float*)d_in[15];
  const float* W_fc1   = (const float*)d_in[16];
  const float* b_fc1   = (const float*)d_in[17];
  const float* W_fc2   = (const float*)d_in[18];
  const float* b_fc2   = (const float*)d_in[19];
  const float* W_out   = (const float*)d_in[20];
  const float* b_out   = (const float*)d_in[21];
  float* outp = (float*)d_out;

  char* ws = (char*)d_ws;
  size_t off = 0;
  auto alloc = [&](size_t bytes) -> char* {
    char* p = ws + off;
    off += (bytes + 255) & ~(size_t)255;
    return p;
  };
  int*    cnt    = (int*)alloc((size_t)N * 4);
  int*    fil    = (int*)alloc((size_t)N * 4);
  size_t  zero_span = (size_t)((char*)fil - (char*)cnt) + ((size_t)N * 4 + 255 & ~(size_t)255);
  int*    rp     = (int*)alloc((size_t)(N + 1) * 4);
  int*    bsum   = (int*)alloc((size_t)NB * 4);
  int*    csr    = (int*)alloc((size_t)E * 4);
  float*  dinv   = (float*)alloc((size_t)N * 4);
  int*    bstart = (int*)alloc((size_t)(NGR + 1) * 4);
  __bf16* WgcnT  = (__bf16*)alloc((size_t)FDIM * FDIM * 2);
  __bf16* WgatT  = (__bf16*)alloc((size_t)FDIM * FDIM * 2);
  __bf16* hbuf   = (__bf16*)alloc((size_t)N * FDIM * 2);
  __bf16* xbuf   = (__bf16*)alloc((size_t)N * FDIM * 2);
  float*  as_    = (float*)alloc((size_t)N * NHEADS * 4);
  float*  ad_    = (float*)alloc((size_t)N * NHEADS * 4);
  float*  minv   = (float*)alloc((size_t)N * NHEADS * 4);
  float*  invden = (float*)alloc((size_t)N * NHEADS * 4);
  float*  aself  = (float*)alloc((size_t)N * NHEADS * 4);
  float*  g      = (float*)alloc((size_t)2 * NGR * 2 * FDIM * 4);   // both branches
  float*  t1     = (float*)alloc((size_t)2 * NGR * 1500 * 4);       // both branches
  float*  xc     = (float*)alloc((size_t)NGR * 256 * 4);
  float*  t2     = (float*)alloc((size_t)NGR * 1024 * 4);
  float*  t3     = (float*)alloc((size_t)NGR * 512 * 4);
  float*  part   = (float*)alloc((size_t)8 * 512 * 512 * 4);        // split-K partials (8 MB)
  if (off > ws_size) return;  // workspace too small: bail (visible as absmax fail)

  wconv2_kernel<<<2 * (FDIM * FDIM) / 256, 256, 0, stream>>>(W_gcn, W_gat, WgcnT, WgatT);

  for (int br = 0; br < 2; br++) {
    hipMemsetAsync(cnt, 0, zero_span, stream);
    const int* srcp = ei[br];
    const int* dstp = ei[br] + E;
    count_kernel<<<(E + 255) / 256, 256, 0, stream>>>(dstp, cnt, E);
    bsum_kernel<<<NB, 256, 0, stream>>>(cnt, bsum, N);
    bscan_kernel<<<1, 256, 0, stream>>>(bsum, NB);
    rpfill_kernel<<<NB, 256, 0, stream>>>(cnt, bsum, rp, dinv, N, E);
    fill_kernel<<<(E + 255) / 256, 256, 0, stream>>>(srcp, dstp, rp, fil, csr, E);

    int g320 = (N + 63) / 64;
    gemm320v3_kernel<float, false><<<g320, 256, 0, stream>>>(
        x[br], WgcnT, hbuf, N, nullptr, nullptr, nullptr, nullptr);
    gcn_agg_kernel<<<(N + 3) / 4, 256, 0, stream>>>(hbuf, rp, csr, dinv, b_gcn, xbuf, N);
    gemm320v3_kernel<__bf16, true><<<g320, 256, 0, stream>>>(
        xbuf, WgatT, hbuf, N, att_src, att_dst, as_, ad_);

    mdenom3_kernel<<<(N * NHEADS + 255) / 256, 256, 0, stream>>>(rp, csr, as_, ad_, minv, invden, aself, N);
    gat_agg_kernel<<<(N + 3) / 4, 256, 0, stream>>>(hbuf, rp, csr, as_, ad_, minv, invden, aself, b_gat, xbuf, N);

    bstart_kernel<<<(N + 256) / 256, 256, 0, stream>>>(bat[br], bstart, N, NGR);
    dim3 gpool(NGR, FDIM / 64);
    pool_kernel<<<gpool, 64, 0, stream>>>(xbuf, bstart, g + (size_t)br * NGR * 2 * FDIM);
  }

  // ---- batched FC head: M=512 covers both branches ----
  {
    dim3 gfc1((512 + BM - 1) / BM, (1500 + BN - 1) / BN);
    gemm_bf16_kernel<3><<<gfc1, 256, 0, stream>>>(g, W_fc_g1, t1, b_fc_g1, 512, 1500, 2 * FDIM, 1500);
    int S = 8, KS = ((1500 + S * BK - 1) / (S * BK)) * BK;
    dim3 gfc2((512 + BM - 1) / BM, (128 + BN - 1) / BN, S);
    gemm_splitk_kernel<<<gfc2, 256, 0, stream>>>(t1, W_fc_g2, part, 512, 128, 1500, KS);
    reduce_kernel<2, true><<<(512 * 128 + 255) / 256, 256, 0, stream>>>(part, xc, b_fc_g2, 512, 128, S, 256);
  }
  {
    dim3 gx1((NGR + BM - 1) / BM, (1024 + BN - 1) / BN);
    gemm_bf16_kernel<3><<<gx1, 256, 0, stream>>>(xc, W_fc1, t2, b_fc1, NGR, 1024, 256, 1024);
    int S = 4, KS = ((1024 + S * BK - 1) / (S * BK)) * BK;
    dim3 gx2((NGR + BM - 1) / BM, (512 + BN - 1) / BN, S);
    gemm_splitk_kernel<<<gx2, 256, 0, stream>>>(t2, W_fc2, part, NGR, 512, 1024, KS);
    reduce_kernel<3, false><<<(NGR * 512 + 255) / 256, 256, 0, stream>>>(part, t3, b_fc2, NGR, 512, S, 512);
    int S2 = 4, KS2 = ((512 + S2 * BK - 1) / (S2 * BK)) * BK;
    dim3 gx3((NGR + BM - 1) / BM, 1, S2);
    gemm_splitk_kernel<<<gx3, 256, 0, stream>>>(t3, W_out, part, NGR, 2, 512, KS2);
    reduce_kernel<2, false><<<(NGR * 2 + 255) / 256, 256, 0, stream>>>(part, outp, b_out, NGR, 2, S2, 2);
  }
}